// Round 1
// baseline (8436.402 us; speedup 1.0000x reference)
//
#include <hip/hip_runtime.h>
#include <math.h>

#define N_NODES 50000
#define N_EDGES 1600000
#define DIM 128          // D == H == 128
#define EPS 1e-5f

// float atomic max via sign-split integer atomics (buffer init to -inf bits).
__device__ __forceinline__ void atomicMaxF(float* addr, float v) {
    if (v >= 0.0f) atomicMax(reinterpret_cast<int*>(addr), __float_as_int(v));
    else           atomicMin(reinterpret_cast<unsigned int*>(addr), __float_as_uint(v));
}

// ---------------- A: init fwd/bwd to -inf, zero stats ----------------
__global__ __launch_bounds__(256) void k_init(uint4* __restrict__ fb, float* __restrict__ stats) {
    int i = blockIdx.x * 256 + threadIdx.x;
    if (i < 512) stats[i] = 0.0f;
    const uint4 p = make_uint4(0xFF800000u, 0xFF800000u, 0xFF800000u, 0xFF800000u);
    if (i < 2 * N_NODES * DIM / 4) fb[i] = p;
}

// ---------------- B: edge scatter-max ----------------
// thread = (edge, quad of 4 h-channels); message read once, 8 atomics out.
__global__ __launch_bounds__(256) void k_scatter(const float4* __restrict__ msg,
                                                 const int* __restrict__ ei,
                                                 float* __restrict__ fwd,
                                                 float* __restrict__ bwd) {
    int gid = blockIdx.x * 256 + threadIdx.x;
    int e = gid >> 5;
    int q = gid & 31;
    if (e >= N_EDGES) return;
    int r = ei[e];            // edge_index[0] = row
    int c = ei[N_EDGES + e];  // edge_index[1] = col
    float4 m = msg[gid];      // msg[e*32 + q]
    float* pf = fwd + (c * DIM + q * 4);
    float* pb = bwd + (r * DIM + q * 4);
    atomicMaxF(pf + 0, m.x); atomicMaxF(pf + 1, m.y);
    atomicMaxF(pf + 2, m.z); atomicMaxF(pf + 3, m.w);
    atomicMaxF(pb + 0, m.x); atomicMaxF(pb + 1, m.y);
    atomicMaxF(pb + 2, m.z); atomicMaxF(pb + 3, m.w);
}

// ---------------- C: h1p = [x|fwd|bwd] @ W1 + b1, col stats ----------------
// block 256 = (j 0..127, s 0..1); 64 rows/block; K split into 6 chunks of 64
// (chunk -> source: 0,1=x  2,3=fwd  4,5=bwd).
__global__ __launch_bounds__(256) void k_gemm1(const float* __restrict__ x,
                                               const float* __restrict__ fwd,
                                               const float* __restrict__ bwd,
                                               const float* __restrict__ W1,
                                               const float* __restrict__ b1,
                                               float* __restrict__ h1p,
                                               float* __restrict__ stats) {
    __shared__ float Wc[64 * 128];
    __shared__ float rows[64 * 64];
    const int tid = threadIdx.x;
    const int j = tid & 127;
    const int s = tid >> 7;
    const int n0 = blockIdx.x * 64;

    float acc[32];
#pragma unroll
    for (int i = 0; i < 32; ++i) acc[i] = 0.0f;

    for (int c = 0; c < 6; ++c) {
        const float* src = (c < 2) ? x : ((c < 4) ? fwd : bwd);
        const bool san = (c >= 2);
        const int koff = (c & 1) * 64;
        // stage W1 chunk [64][128]
#pragma unroll
        for (int i = 0; i < 32; ++i) {
            int idx = tid + i * 256;
            Wc[idx] = W1[c * 64 * 128 + idx];
        }
        // stage 64 rows x 64 k
#pragma unroll
        for (int i = 0; i < 16; ++i) {
            int idx = tid + i * 256;
            int r = idx >> 6, k = idx & 63;
            int n = n0 + r;
            float v = 0.0f;
            if (n < N_NODES) {
                v = src[n * DIM + koff + k];
                if (san && __float_as_uint(v) == 0xFF800000u) v = 0.0f;  // empty segment -> 0
            }
            rows[idx] = v;
        }
        __syncthreads();
#pragma unroll 2
        for (int k4 = 0; k4 < 16; ++k4) {
            float w0 = Wc[(k4 * 4 + 0) * 128 + j];
            float w1 = Wc[(k4 * 4 + 1) * 128 + j];
            float w2 = Wc[(k4 * 4 + 2) * 128 + j];
            float w3 = Wc[(k4 * 4 + 3) * 128 + j];
#pragma unroll
            for (int ri = 0; ri < 32; ++ri) {
                const float4 rv = *reinterpret_cast<const float4*>(&rows[(s + 2 * ri) * 64 + k4 * 4]);
                float a = acc[ri];
                a = fmaf(rv.x, w0, a);
                a = fmaf(rv.y, w1, a);
                a = fmaf(rv.z, w2, a);
                a = fmaf(rv.w, w3, a);
                acc[ri] = a;
            }
        }
        __syncthreads();
    }
    const float bj = b1[j];
    float sum = 0.0f, sq = 0.0f;
#pragma unroll
    for (int ri = 0; ri < 32; ++ri) {
        int n = n0 + s + 2 * ri;
        if (n < N_NODES) {
            float v = acc[ri] + bj;
            h1p[n * DIM + j] = v;
            sum += v;
            sq += v * v;
        }
    }
    atomicAdd(&stats[j], sum);
    atomicAdd(&stats[128 + j], sq);
}

// ---------------- D: h1 = relu(BN1(h1p)); h2p = h1 @ W2 + b2; col stats2 ----------------
__global__ __launch_bounds__(256) void k_gemm2(const float* __restrict__ h1p,
                                               const float* __restrict__ W2,
                                               const float* __restrict__ b2,
                                               const float* __restrict__ g1,
                                               const float* __restrict__ be1,
                                               float* __restrict__ h2p,
                                               float* __restrict__ stats) {
    __shared__ float Wc[64 * 128];
    __shared__ float rows[64 * 128];
    __shared__ float ssc[128], ssh[128];
    const int tid = threadIdx.x;
    const int j = tid & 127;
    const int s = tid >> 7;
    const int n0 = blockIdx.x * 64;

    if (tid < 128) {
        float mu = stats[tid] * (1.0f / N_NODES);
        float var = stats[128 + tid] * (1.0f / N_NODES) - mu * mu;
        float sc = rsqrtf(var + EPS) * g1[tid];
        ssc[tid] = sc;
        ssh[tid] = be1[tid] - mu * sc;
    }
    __syncthreads();
    // stage post-BN1+relu rows [64][128]
#pragma unroll
    for (int i = 0; i < 32; ++i) {
        int idx = tid + i * 256;
        int r = idx >> 7, k = idx & 127;
        int n = n0 + r;
        float v = 0.0f;
        if (n < N_NODES) {
            v = h1p[n * DIM + k];
            v = fmaxf(v * ssc[k] + ssh[k], 0.0f);
        }
        rows[idx] = v;
    }
    float acc[32];
#pragma unroll
    for (int i = 0; i < 32; ++i) acc[i] = 0.0f;

    for (int c = 0; c < 2; ++c) {
        __syncthreads();
#pragma unroll
        for (int i = 0; i < 32; ++i) {
            int idx = tid + i * 256;
            Wc[idx] = W2[c * 64 * 128 + idx];
        }
        __syncthreads();
#pragma unroll 2
        for (int k4 = 0; k4 < 16; ++k4) {
            float w0 = Wc[(k4 * 4 + 0) * 128 + j];
            float w1 = Wc[(k4 * 4 + 1) * 128 + j];
            float w2 = Wc[(k4 * 4 + 2) * 128 + j];
            float w3 = Wc[(k4 * 4 + 3) * 128 + j];
#pragma unroll
            for (int ri = 0; ri < 32; ++ri) {
                const float4 rv = *reinterpret_cast<const float4*>(
                    &rows[(s + 2 * ri) * 128 + c * 64 + k4 * 4]);
                float a = acc[ri];
                a = fmaf(rv.x, w0, a);
                a = fmaf(rv.y, w1, a);
                a = fmaf(rv.z, w2, a);
                a = fmaf(rv.w, w3, a);
                acc[ri] = a;
            }
        }
    }
    const float bj = b2[j];
    float sum = 0.0f, sq = 0.0f;
#pragma unroll
    for (int ri = 0; ri < 32; ++ri) {
        int n = n0 + s + 2 * ri;
        if (n < N_NODES) {
            float v = acc[ri] + bj;
            h2p[n * DIM + j] = v;
            sum += v;
            sq += v * v;
        }
    }
    atomicAdd(&stats[256 + j], sum);
    atomicAdd(&stats[384 + j], sq);
}

// ---------------- E: h = relu(BN2(h2p)) -> out; att = sigmoid(h @ Wa + ba) ----------------
__global__ __launch_bounds__(256) void k_final(const float* __restrict__ h2p,
                                               const float* __restrict__ stats,
                                               const float* __restrict__ g2,
                                               const float* __restrict__ be2,
                                               const float* __restrict__ Wa,
                                               const float* __restrict__ ba,
                                               float* __restrict__ out) {
    const int lane = threadIdx.x & 63;
    const int wv = threadIdx.x >> 6;
    const int n = blockIdx.x * 4 + wv;
    if (n >= N_NODES) return;
    const int j0 = lane, j1 = lane + 64;

    float mu0 = stats[256 + j0] * (1.0f / N_NODES);
    float var0 = stats[384 + j0] * (1.0f / N_NODES) - mu0 * mu0;
    float sc0 = rsqrtf(var0 + EPS) * g2[j0];
    float sh0 = be2[j0] - mu0 * sc0;
    float mu1 = stats[256 + j1] * (1.0f / N_NODES);
    float var1 = stats[384 + j1] * (1.0f / N_NODES) - mu1 * mu1;
    float sc1 = rsqrtf(var1 + EPS) * g2[j1];
    float sh1 = be2[j1] - mu1 * sc1;

    float v0 = fmaxf(h2p[n * DIM + j0] * sc0 + sh0, 0.0f);
    float v1 = fmaxf(h2p[n * DIM + j1] * sc1 + sh1, 0.0f);
    out[n * DIM + j0] = v0;
    out[n * DIM + j1] = v1;

    float p = v0 * Wa[j0] + v1 * Wa[j1];
#pragma unroll
    for (int off = 32; off > 0; off >>= 1) p += __shfl_down(p, off);
    if (lane == 0) out[N_NODES * DIM + n] = 1.0f / (1.0f + expf(-(p + ba[0])));
}

extern "C" void kernel_launch(void* const* d_in, const int* in_sizes, int n_in,
                              void* d_out, int out_size, void* d_ws, size_t ws_size,
                              hipStream_t stream) {
    const float* x   = (const float*)d_in[0];
    const float* msg = (const float*)d_in[1];
    const float* W1  = (const float*)d_in[2];
    const float* b1  = (const float*)d_in[3];
    const float* g1  = (const float*)d_in[4];
    const float* be1 = (const float*)d_in[5];
    const float* W2  = (const float*)d_in[6];
    const float* b2  = (const float*)d_in[7];
    const float* g2  = (const float*)d_in[8];
    const float* be2 = (const float*)d_in[9];
    const float* Wa  = (const float*)d_in[10];
    const float* ba  = (const float*)d_in[11];
    const int*   ei  = (const int*)d_in[12];

    float* ws    = (float*)d_ws;
    float* stats = ws;                       // 512 floats
    float* fwd   = ws + 512;                 // N*H
    float* bwd   = fwd + N_NODES * DIM;      // N*H
    float* h1p   = (float*)d_out;            // reuse out buffer as scratch
    float* h2p   = fwd;                      // fwd dead after gemm1
    float* out   = (float*)d_out;

    k_init<<<12500, 256, 0, stream>>>((uint4*)fwd, stats);
    k_scatter<<<(N_EDGES * 32) / 256, 256, 0, stream>>>((const float4*)msg, ei, fwd, bwd);
    k_gemm1<<<(N_NODES + 63) / 64, 256, 0, stream>>>(x, fwd, bwd, W1, b1, h1p, stats);
    k_gemm2<<<(N_NODES + 63) / 64, 256, 0, stream>>>(h1p, W2, b2, g1, be1, h2p, stats);
    k_final<<<(N_NODES + 3) / 4, 256, 0, stream>>>(h2p, stats, g2, be2, Wa, ba, out);
}

// Round 2
// 1231.783 us; speedup vs baseline: 6.8489x; 6.8489x over previous
//
#include <hip/hip_runtime.h>
#include <math.h>

#define N_NODES 50000
#define N_EDGES 1600000
#define DIM 128          // D == H == 128
#define EPS 1e-5f

// ---------------- A: zero stats + histograms ----------------
__global__ __launch_bounds__(256) void k_init(float* __restrict__ stats, int* __restrict__ cnt) {
    int i = blockIdx.x * 256 + threadIdx.x;
    if (i < 512) stats[i] = 0.0f;
    if (i < 2 * N_NODES) cnt[i] = 0;
}

// ---------------- B1: histogram of col (fwd) and row (bwd) ----------------
__global__ __launch_bounds__(256) void k_count(const int* __restrict__ ei, int* __restrict__ cnt) {
    int e = blockIdx.x * 256 + threadIdx.x;
    if (e >= N_EDGES) return;
    int r = ei[e];
    int c = ei[N_EDGES + e];
    atomicAdd(&cnt[c], 1);              // col buckets
    atomicAdd(&cnt[N_NODES + r], 1);    // row buckets
}

// ---------------- B2: exclusive scan (1 block per array) ----------------
__global__ __launch_bounds__(1024) void k_scan(const int* __restrict__ cnt, int* __restrict__ off) {
    __shared__ int buf[1024];
    __shared__ int carry;
    const int b = blockIdx.x;           // 0: col, 1: row
    const int t = threadIdx.x;
    const int* src = cnt + b * N_NODES;
    int* dst = off + b * N_NODES;
    if (t == 0) carry = 0;
    __syncthreads();
    for (int base = 0; base < N_NODES; base += 1024) {
        int i = base + t;
        int v = (i < N_NODES) ? src[i] : 0;
        buf[t] = v;
        __syncthreads();
        for (int d = 1; d < 1024; d <<= 1) {
            int add = (t >= d) ? buf[t - d] : 0;
            __syncthreads();
            buf[t] += add;
            __syncthreads();
        }
        if (i < N_NODES) dst[i] = buf[t] - v + carry;   // exclusive
        __syncthreads();
        if (t == 1023) carry += buf[1023];
        __syncthreads();
    }
}

// ---------------- B3: fill buckets (off becomes inclusive scan after this) ----------------
__global__ __launch_bounds__(256) void k_fill(const int* __restrict__ ei, int* __restrict__ off,
                                              int* __restrict__ e_col, int* __restrict__ e_row) {
    int e = blockIdx.x * 256 + threadIdx.x;
    if (e >= N_EDGES) return;
    int r = ei[e];
    int c = ei[N_EDGES + e];
    e_col[atomicAdd(&off[c], 1)] = e;
    e_row[atomicAdd(&off[N_NODES + r], 1)] = e;
}

// ---------------- B4: gather-max. block = (node,dir), thread = channel ----------------
__global__ __launch_bounds__(128) void k_gather(const float* __restrict__ msg,
                                                const int* __restrict__ elist,  // e_col then e_row
                                                const int* __restrict__ off,    // inclusive, col then row
                                                float* __restrict__ fwd,
                                                float* __restrict__ bwd) {
    int b = blockIdx.x;
    int dir = (b >= N_NODES);
    int n = dir ? b - N_NODES : b;
    const int* eo = off + dir * N_NODES;
    const int* el = elist + (size_t)dir * N_EDGES;
    int start = n ? eo[n - 1] : 0;
    int end = eo[n];
    int j = threadIdx.x;
    float v = -INFINITY;
    int p = start;
    for (; p + 1 < end; p += 2) {
        int e0 = el[p], e1 = el[p + 1];
        float m0 = msg[(size_t)e0 * DIM + j];
        float m1 = msg[(size_t)e1 * DIM + j];
        v = fmaxf(v, fmaxf(m0, m1));
    }
    if (p < end) v = fmaxf(v, msg[(size_t)el[p] * DIM + j]);
    float* dst = dir ? bwd : fwd;
    dst[n * DIM + j] = (start < end) ? v : 0.0f;   // empty segment -> 0 (torch_scatter semantics)
}

// ---------------- C: h1p = [x|fwd|bwd] @ W1 + b1, col stats ----------------
__global__ __launch_bounds__(256) void k_gemm1(const float* __restrict__ x,
                                               const float* __restrict__ fwd,
                                               const float* __restrict__ bwd,
                                               const float* __restrict__ W1,
                                               const float* __restrict__ b1,
                                               float* __restrict__ h1p,
                                               float* __restrict__ stats) {
    __shared__ float Wc[64 * 128];
    __shared__ float rows[64 * 64];
    const int tid = threadIdx.x;
    const int j = tid & 127;
    const int s = tid >> 7;
    const int n0 = blockIdx.x * 64;

    float acc[32];
#pragma unroll
    for (int i = 0; i < 32; ++i) acc[i] = 0.0f;

    for (int c = 0; c < 6; ++c) {
        const float* src = (c < 2) ? x : ((c < 4) ? fwd : bwd);
        const int koff = (c & 1) * 64;
#pragma unroll
        for (int i = 0; i < 32; ++i) {
            int idx = tid + i * 256;
            Wc[idx] = W1[c * 64 * 128 + idx];
        }
#pragma unroll
        for (int i = 0; i < 16; ++i) {
            int idx = tid + i * 256;
            int r = idx >> 6, k = idx & 63;
            int n = n0 + r;
            rows[idx] = (n < N_NODES) ? src[n * DIM + koff + k] : 0.0f;
        }
        __syncthreads();
#pragma unroll 2
        for (int k4 = 0; k4 < 16; ++k4) {
            float w0 = Wc[(k4 * 4 + 0) * 128 + j];
            float w1 = Wc[(k4 * 4 + 1) * 128 + j];
            float w2 = Wc[(k4 * 4 + 2) * 128 + j];
            float w3 = Wc[(k4 * 4 + 3) * 128 + j];
#pragma unroll
            for (int ri = 0; ri < 32; ++ri) {
                const float4 rv = *reinterpret_cast<const float4*>(&rows[(s + 2 * ri) * 64 + k4 * 4]);
                float a = acc[ri];
                a = fmaf(rv.x, w0, a);
                a = fmaf(rv.y, w1, a);
                a = fmaf(rv.z, w2, a);
                a = fmaf(rv.w, w3, a);
                acc[ri] = a;
            }
        }
        __syncthreads();
    }
    const float bj = b1[j];
    float sum = 0.0f, sq = 0.0f;
#pragma unroll
    for (int ri = 0; ri < 32; ++ri) {
        int n = n0 + s + 2 * ri;
        if (n < N_NODES) {
            float v = acc[ri] + bj;
            h1p[n * DIM + j] = v;
            sum += v;
            sq += v * v;
        }
    }
    atomicAdd(&stats[j], sum);
    atomicAdd(&stats[128 + j], sq);
}

// ---------------- D: h1 = relu(BN1(h1p)); h2p = h1 @ W2 + b2; col stats2 ----------------
__global__ __launch_bounds__(256) void k_gemm2(const float* __restrict__ h1p,
                                               const float* __restrict__ W2,
                                               const float* __restrict__ b2,
                                               const float* __restrict__ g1,
                                               const float* __restrict__ be1,
                                               float* __restrict__ h2p,
                                               float* __restrict__ stats) {
    __shared__ float Wc[64 * 128];
    __shared__ float rows[64 * 128];
    __shared__ float ssc[128], ssh[128];
    const int tid = threadIdx.x;
    const int j = tid & 127;
    const int s = tid >> 7;
    const int n0 = blockIdx.x * 64;

    if (tid < 128) {
        float mu = stats[tid] * (1.0f / N_NODES);
        float var = stats[128 + tid] * (1.0f / N_NODES) - mu * mu;
        float sc = rsqrtf(var + EPS) * g1[tid];
        ssc[tid] = sc;
        ssh[tid] = be1[tid] - mu * sc;
    }
    __syncthreads();
#pragma unroll
    for (int i = 0; i < 32; ++i) {
        int idx = tid + i * 256;
        int r = idx >> 7, k = idx & 127;
        int n = n0 + r;
        float v = 0.0f;
        if (n < N_NODES) {
            v = h1p[n * DIM + k];
            v = fmaxf(v * ssc[k] + ssh[k], 0.0f);
        }
        rows[idx] = v;
    }
    float acc[32];
#pragma unroll
    for (int i = 0; i < 32; ++i) acc[i] = 0.0f;

    for (int c = 0; c < 2; ++c) {
        __syncthreads();
#pragma unroll
        for (int i = 0; i < 32; ++i) {
            int idx = tid + i * 256;
            Wc[idx] = W2[c * 64 * 128 + idx];
        }
        __syncthreads();
#pragma unroll 2
        for (int k4 = 0; k4 < 16; ++k4) {
            float w0 = Wc[(k4 * 4 + 0) * 128 + j];
            float w1 = Wc[(k4 * 4 + 1) * 128 + j];
            float w2 = Wc[(k4 * 4 + 2) * 128 + j];
            float w3 = Wc[(k4 * 4 + 3) * 128 + j];
#pragma unroll
            for (int ri = 0; ri < 32; ++ri) {
                const float4 rv = *reinterpret_cast<const float4*>(
                    &rows[(s + 2 * ri) * 128 + c * 64 + k4 * 4]);
                float a = acc[ri];
                a = fmaf(rv.x, w0, a);
                a = fmaf(rv.y, w1, a);
                a = fmaf(rv.z, w2, a);
                a = fmaf(rv.w, w3, a);
                acc[ri] = a;
            }
        }
    }
    const float bj = b2[j];
    float sum = 0.0f, sq = 0.0f;
#pragma unroll
    for (int ri = 0; ri < 32; ++ri) {
        int n = n0 + s + 2 * ri;
        if (n < N_NODES) {
            float v = acc[ri] + bj;
            h2p[n * DIM + j] = v;
            sum += v;
            sq += v * v;
        }
    }
    atomicAdd(&stats[256 + j], sum);
    atomicAdd(&stats[384 + j], sq);
}

// ---------------- E: h = relu(BN2(h2p)) -> out; att = sigmoid(h @ Wa + ba) ----------------
__global__ __launch_bounds__(256) void k_final(const float* __restrict__ h2p,
                                               const float* __restrict__ stats,
                                               const float* __restrict__ g2,
                                               const float* __restrict__ be2,
                                               const float* __restrict__ Wa,
                                               const float* __restrict__ ba,
                                               float* __restrict__ out) {
    const int lane = threadIdx.x & 63;
    const int wv = threadIdx.x >> 6;
    const int n = blockIdx.x * 4 + wv;
    if (n >= N_NODES) return;
    const int j0 = lane, j1 = lane + 64;

    float mu0 = stats[256 + j0] * (1.0f / N_NODES);
    float var0 = stats[384 + j0] * (1.0f / N_NODES) - mu0 * mu0;
    float sc0 = rsqrtf(var0 + EPS) * g2[j0];
    float sh0 = be2[j0] - mu0 * sc0;
    float mu1 = stats[256 + j1] * (1.0f / N_NODES);
    float var1 = stats[384 + j1] * (1.0f / N_NODES) - mu1 * mu1;
    float sc1 = rsqrtf(var1 + EPS) * g2[j1];
    float sh1 = be2[j1] - mu1 * sc1;

    float v0 = fmaxf(h2p[n * DIM + j0] * sc0 + sh0, 0.0f);
    float v1 = fmaxf(h2p[n * DIM + j1] * sc1 + sh1, 0.0f);
    out[n * DIM + j0] = v0;
    out[n * DIM + j1] = v1;

    float p = v0 * Wa[j0] + v1 * Wa[j1];
#pragma unroll
    for (int off = 32; off > 0; off >>= 1) p += __shfl_down(p, off);
    if (lane == 0) out[N_NODES * DIM + n] = 1.0f / (1.0f + expf(-(p + ba[0])));
}

extern "C" void kernel_launch(void* const* d_in, const int* in_sizes, int n_in,
                              void* d_out, int out_size, void* d_ws, size_t ws_size,
                              hipStream_t stream) {
    const float* x   = (const float*)d_in[0];
    const float* msg = (const float*)d_in[1];
    const float* W1  = (const float*)d_in[2];
    const float* b1  = (const float*)d_in[3];
    const float* g1  = (const float*)d_in[4];
    const float* be1 = (const float*)d_in[5];
    const float* W2  = (const float*)d_in[6];
    const float* b2  = (const float*)d_in[7];
    const float* g2  = (const float*)d_in[8];
    const float* be2 = (const float*)d_in[9];
    const float* Wa  = (const float*)d_in[10];
    const float* ba  = (const float*)d_in[11];
    const int*   ei  = (const int*)d_in[12];

    float* ws    = (float*)d_ws;
    float* stats = ws;                       // 512 floats
    float* fwd   = ws + 512;                 // N*H
    float* bwd   = fwd + N_NODES * DIM;      // N*H
    int*   ip    = (int*)(bwd + N_NODES * DIM);
    int*   cnt   = ip;                       // 2N (col then row)
    int*   off   = ip + 2 * N_NODES;         // 2N (col then row)

    // edge lists live in d_out — dead before gemm1 writes h1p there
    int* e_col = (int*)d_out;                // E ints
    int* e_row = e_col + N_EDGES;            // E ints (2E*4 = 12.8MB < 25.8MB)

    float* h1p = (float*)d_out;
    float* h2p = fwd;                        // fwd dead after gemm1
    float* out = (float*)d_out;

    k_init<<<(2 * N_NODES + 255) / 256, 256, 0, stream>>>(stats, cnt);
    k_count<<<N_EDGES / 256, 256, 0, stream>>>(ei, cnt);
    k_scan<<<2, 1024, 0, stream>>>(cnt, off);
    k_fill<<<N_EDGES / 256, 256, 0, stream>>>(ei, off, e_col, e_row);
    k_gather<<<2 * N_NODES, 128, 0, stream>>>(msg, e_col, off, fwd, bwd);
    k_gemm1<<<(N_NODES + 63) / 64, 256, 0, stream>>>(x, fwd, bwd, W1, b1, h1p, stats);
    k_gemm2<<<(N_NODES + 63) / 64, 256, 0, stream>>>(h1p, W2, b2, g1, be1, h2p, stats);
    k_final<<<(N_NODES + 3) / 4, 256, 0, stream>>>(h2p, stats, g2, be2, Wa, ba, out);
}

// Round 3
// 1188.971 us; speedup vs baseline: 7.0956x; 1.0360x over previous
//
#include <hip/hip_runtime.h>
#include <math.h>

#define N_NODES 50000
#define N_EDGES 1600000
#define DIM 128          // D == H == 128
#define EPS 1e-5f

// ---------------- A: zero stats + histograms ----------------
__global__ __launch_bounds__(256) void k_init(float* __restrict__ stats, int* __restrict__ cnt) {
    int i = blockIdx.x * 256 + threadIdx.x;
    if (i < 512) stats[i] = 0.0f;
    if (i < 2 * N_NODES) cnt[i] = 0;
}

// ---------------- B1: histogram of col (fwd) and row (bwd), 4 edges/thread ----------------
__global__ __launch_bounds__(256) void k_count(const int* __restrict__ ei, int* __restrict__ cnt) {
    int t = blockIdx.x * 256 + threadIdx.x;
    if (t >= N_EDGES / 4) return;
    int4 r4 = reinterpret_cast<const int4*>(ei)[t];
    int4 c4 = reinterpret_cast<const int4*>(ei + N_EDGES)[t];
    atomicAdd(&cnt[c4.x], 1); atomicAdd(&cnt[c4.y], 1);
    atomicAdd(&cnt[c4.z], 1); atomicAdd(&cnt[c4.w], 1);
    atomicAdd(&cnt[N_NODES + r4.x], 1); atomicAdd(&cnt[N_NODES + r4.y], 1);
    atomicAdd(&cnt[N_NODES + r4.z], 1); atomicAdd(&cnt[N_NODES + r4.w], 1);
}

// ---------------- B2: exclusive scan (1 block per array) ----------------
__global__ __launch_bounds__(1024) void k_scan(const int* __restrict__ cnt, int* __restrict__ off) {
    __shared__ int buf[1024];
    __shared__ int carry;
    const int b = blockIdx.x;           // 0: col, 1: row
    const int t = threadIdx.x;
    const int* src = cnt + b * N_NODES;
    int* dst = off + b * N_NODES;
    if (t == 0) carry = 0;
    __syncthreads();
    for (int base = 0; base < N_NODES; base += 1024) {
        int i = base + t;
        int v = (i < N_NODES) ? src[i] : 0;
        buf[t] = v;
        __syncthreads();
        for (int d = 1; d < 1024; d <<= 1) {
            int add = (t >= d) ? buf[t - d] : 0;
            __syncthreads();
            buf[t] += add;
            __syncthreads();
        }
        if (i < N_NODES) dst[i] = buf[t] - v + carry;   // exclusive
        __syncthreads();
        if (t == 1023) carry += buf[1023];
        __syncthreads();
    }
}

// ---------------- B3: fill buckets (off becomes inclusive scan after this) ----------------
__global__ __launch_bounds__(256) void k_fill(const int* __restrict__ ei, int* __restrict__ off,
                                              int* __restrict__ e_col, int* __restrict__ e_row) {
    int t = blockIdx.x * 256 + threadIdx.x;
    if (t >= N_EDGES / 4) return;
    int4 r4 = reinterpret_cast<const int4*>(ei)[t];
    int4 c4 = reinterpret_cast<const int4*>(ei + N_EDGES)[t];
    int e = t * 4;
    e_col[atomicAdd(&off[c4.x], 1)] = e + 0;
    e_col[atomicAdd(&off[c4.y], 1)] = e + 1;
    e_col[atomicAdd(&off[c4.z], 1)] = e + 2;
    e_col[atomicAdd(&off[c4.w], 1)] = e + 3;
    e_row[atomicAdd(&off[N_NODES + r4.x], 1)] = e + 0;
    e_row[atomicAdd(&off[N_NODES + r4.y], 1)] = e + 1;
    e_row[atomicAdd(&off[N_NODES + r4.z], 1)] = e + 2;
    e_row[atomicAdd(&off[N_NODES + r4.w], 1)] = e + 3;
}

// ---------------- B4: gather-max. wave = (node,dir); float4 loads; 4 rows in flight ----------------
__global__ __launch_bounds__(256) void k_gather(const float4* __restrict__ msgv,
                                                const int* __restrict__ elist,  // e_col then e_row
                                                const int* __restrict__ off,    // inclusive, col then row
                                                float* __restrict__ fwd,
                                                float* __restrict__ bwd) {
    const int wid = blockIdx.x * 4 + (threadIdx.x >> 6);   // 0 .. 2N-1
    const int dir = (wid >= N_NODES);
    const int n = dir ? wid - N_NODES : wid;
    const int lane = threadIdx.x & 63;
    const int q = lane & 31;        // channel quad: channels q*4..q*4+3
    const int h = lane >> 5;        // row parity (half-wave)
    const int* eo = off + dir * N_NODES;
    const int* el = elist + (size_t)dir * N_EDGES;
    const int start = n ? eo[n - 1] : 0;
    const int end = eo[n];

    float4 acc = make_float4(-INFINITY, -INFINITY, -INFINITY, -INFINITY);
    int p = start + h;
    // unroll 2: this half-wave handles edges start+h, start+h+2, ... (2 per iter)
    for (; p + 2 < end; p += 4) {
        int e0 = el[p], e1 = el[p + 2];
        float4 m0 = msgv[(size_t)e0 * 32 + q];
        float4 m1 = msgv[(size_t)e1 * 32 + q];
        m0.x = fmaxf(m0.x, m1.x); m0.y = fmaxf(m0.y, m1.y);
        m0.z = fmaxf(m0.z, m1.z); m0.w = fmaxf(m0.w, m1.w);
        acc.x = fmaxf(acc.x, m0.x); acc.y = fmaxf(acc.y, m0.y);
        acc.z = fmaxf(acc.z, m0.z); acc.w = fmaxf(acc.w, m0.w);
    }
    if (p < end) {
        float4 m = msgv[(size_t)el[p] * 32 + q];
        acc.x = fmaxf(acc.x, m.x); acc.y = fmaxf(acc.y, m.y);
        acc.z = fmaxf(acc.z, m.z); acc.w = fmaxf(acc.w, m.w);
    }
    // combine the two half-waves
    acc.x = fmaxf(acc.x, __shfl_xor(acc.x, 32));
    acc.y = fmaxf(acc.y, __shfl_xor(acc.y, 32));
    acc.z = fmaxf(acc.z, __shfl_xor(acc.z, 32));
    acc.w = fmaxf(acc.w, __shfl_xor(acc.w, 32));

    if (h == 0) {
        if (start >= end) acc = make_float4(0.0f, 0.0f, 0.0f, 0.0f);  // empty segment -> 0
        float* dst = dir ? bwd : fwd;
        reinterpret_cast<float4*>(dst + n * DIM)[q] = acc;
    }
}

// ---------------- C: h1p = [x|fwd|bwd] @ W1 + b1, col stats ----------------
__global__ __launch_bounds__(256) void k_gemm1(const float* __restrict__ x,
                                               const float* __restrict__ fwd,
                                               const float* __restrict__ bwd,
                                               const float* __restrict__ W1,
                                               const float* __restrict__ b1,
                                               float* __restrict__ h1p,
                                               float* __restrict__ stats) {
    __shared__ float Wc[64 * 128];
    __shared__ float rows[64 * 64];
    const int tid = threadIdx.x;
    const int j = tid & 127;
    const int s = tid >> 7;
    const int n0 = blockIdx.x * 64;

    float acc[32];
#pragma unroll
    for (int i = 0; i < 32; ++i) acc[i] = 0.0f;

    for (int c = 0; c < 6; ++c) {
        const float* src = (c < 2) ? x : ((c < 4) ? fwd : bwd);
        const int koff = (c & 1) * 64;
#pragma unroll
        for (int i = 0; i < 32; ++i) {
            int idx = tid + i * 256;
            Wc[idx] = W1[c * 64 * 128 + idx];
        }
#pragma unroll
        for (int i = 0; i < 16; ++i) {
            int idx = tid + i * 256;
            int r = idx >> 6, k = idx & 63;
            int n = n0 + r;
            rows[idx] = (n < N_NODES) ? src[n * DIM + koff + k] : 0.0f;
        }
        __syncthreads();
#pragma unroll 2
        for (int k4 = 0; k4 < 16; ++k4) {
            float w0 = Wc[(k4 * 4 + 0) * 128 + j];
            float w1 = Wc[(k4 * 4 + 1) * 128 + j];
            float w2 = Wc[(k4 * 4 + 2) * 128 + j];
            float w3 = Wc[(k4 * 4 + 3) * 128 + j];
#pragma unroll
            for (int ri = 0; ri < 32; ++ri) {
                const float4 rv = *reinterpret_cast<const float4*>(&rows[(s + 2 * ri) * 64 + k4 * 4]);
                float a = acc[ri];
                a = fmaf(rv.x, w0, a);
                a = fmaf(rv.y, w1, a);
                a = fmaf(rv.z, w2, a);
                a = fmaf(rv.w, w3, a);
                acc[ri] = a;
            }
        }
        __syncthreads();
    }
    const float bj = b1[j];
    float sum = 0.0f, sq = 0.0f;
#pragma unroll
    for (int ri = 0; ri < 32; ++ri) {
        int n = n0 + s + 2 * ri;
        if (n < N_NODES) {
            float v = acc[ri] + bj;
            h1p[n * DIM + j] = v;
            sum += v;
            sq += v * v;
        }
    }
    atomicAdd(&stats[j], sum);
    atomicAdd(&stats[128 + j], sq);
}

// ---------------- D: h1 = relu(BN1(h1p)); h2p = h1 @ W2 + b2; col stats2 ----------------
__global__ __launch_bounds__(256) void k_gemm2(const float* __restrict__ h1p,
                                               const float* __restrict__ W2,
                                               const float* __restrict__ b2,
                                               const float* __restrict__ g1,
                                               const float* __restrict__ be1,
                                               float* __restrict__ h2p,
                                               float* __restrict__ stats) {
    __shared__ float Wc[64 * 128];
    __shared__ float rows[64 * 128];
    __shared__ float ssc[128], ssh[128];
    const int tid = threadIdx.x;
    const int j = tid & 127;
    const int s = tid >> 7;
    const int n0 = blockIdx.x * 64;

    if (tid < 128) {
        float mu = stats[tid] * (1.0f / N_NODES);
        float var = stats[128 + tid] * (1.0f / N_NODES) - mu * mu;
        float sc = rsqrtf(var + EPS) * g1[tid];
        ssc[tid] = sc;
        ssh[tid] = be1[tid] - mu * sc;
    }
    __syncthreads();
#pragma unroll
    for (int i = 0; i < 32; ++i) {
        int idx = tid + i * 256;
        int r = idx >> 7, k = idx & 127;
        int n = n0 + r;
        float v = 0.0f;
        if (n < N_NODES) {
            v = h1p[n * DIM + k];
            v = fmaxf(v * ssc[k] + ssh[k], 0.0f);
        }
        rows[idx] = v;
    }
    float acc[32];
#pragma unroll
    for (int i = 0; i < 32; ++i) acc[i] = 0.0f;

    for (int c = 0; c < 2; ++c) {
        __syncthreads();
#pragma unroll
        for (int i = 0; i < 32; ++i) {
            int idx = tid + i * 256;
            Wc[idx] = W2[c * 64 * 128 + idx];
        }
        __syncthreads();
#pragma unroll 2
        for (int k4 = 0; k4 < 16; ++k4) {
            float w0 = Wc[(k4 * 4 + 0) * 128 + j];
            float w1 = Wc[(k4 * 4 + 1) * 128 + j];
            float w2 = Wc[(k4 * 4 + 2) * 128 + j];
            float w3 = Wc[(k4 * 4 + 3) * 128 + j];
#pragma unroll
            for (int ri = 0; ri < 32; ++ri) {
                const float4 rv = *reinterpret_cast<const float4*>(
                    &rows[(s + 2 * ri) * 128 + c * 64 + k4 * 4]);
                float a = acc[ri];
                a = fmaf(rv.x, w0, a);
                a = fmaf(rv.y, w1, a);
                a = fmaf(rv.z, w2, a);
                a = fmaf(rv.w, w3, a);
                acc[ri] = a;
            }
        }
    }
    const float bj = b2[j];
    float sum = 0.0f, sq = 0.0f;
#pragma unroll
    for (int ri = 0; ri < 32; ++ri) {
        int n = n0 + s + 2 * ri;
        if (n < N_NODES) {
            float v = acc[ri] + bj;
            h2p[n * DIM + j] = v;
            sum += v;
            sq += v * v;
        }
    }
    atomicAdd(&stats[256 + j], sum);
    atomicAdd(&stats[384 + j], sq);
}

// ---------------- E: h = relu(BN2(h2p)) -> out; att = sigmoid(h @ Wa + ba) ----------------
__global__ __launch_bounds__(256) void k_final(const float* __restrict__ h2p,
                                               const float* __restrict__ stats,
                                               const float* __restrict__ g2,
                                               const float* __restrict__ be2,
                                               const float* __restrict__ Wa,
                                               const float* __restrict__ ba,
                                               float* __restrict__ out) {
    const int lane = threadIdx.x & 63;
    const int wv = threadIdx.x >> 6;
    const int n = blockIdx.x * 4 + wv;
    if (n >= N_NODES) return;
    const int j0 = lane, j1 = lane + 64;

    float mu0 = stats[256 + j0] * (1.0f / N_NODES);
    float var0 = stats[384 + j0] * (1.0f / N_NODES) - mu0 * mu0;
    float sc0 = rsqrtf(var0 + EPS) * g2[j0];
    float sh0 = be2[j0] - mu0 * sc0;
    float mu1 = stats[256 + j1] * (1.0f / N_NODES);
    float var1 = stats[384 + j1] * (1.0f / N_NODES) - mu1 * mu1;
    float sc1 = rsqrtf(var1 + EPS) * g2[j1];
    float sh1 = be2[j1] - mu1 * sc1;

    float v0 = fmaxf(h2p[n * DIM + j0] * sc0 + sh0, 0.0f);
    float v1 = fmaxf(h2p[n * DIM + j1] * sc1 + sh1, 0.0f);
    out[n * DIM + j0] = v0;
    out[n * DIM + j1] = v1;

    float p = v0 * Wa[j0] + v1 * Wa[j1];
#pragma unroll
    for (int off = 32; off > 0; off >>= 1) p += __shfl_down(p, off);
    if (lane == 0) out[N_NODES * DIM + n] = 1.0f / (1.0f + expf(-(p + ba[0])));
}

extern "C" void kernel_launch(void* const* d_in, const int* in_sizes, int n_in,
                              void* d_out, int out_size, void* d_ws, size_t ws_size,
                              hipStream_t stream) {
    const float* x   = (const float*)d_in[0];
    const float* msg = (const float*)d_in[1];
    const float* W1  = (const float*)d_in[2];
    const float* b1  = (const float*)d_in[3];
    const float* g1  = (const float*)d_in[4];
    const float* be1 = (const float*)d_in[5];
    const float* W2  = (const float*)d_in[6];
    const float* b2  = (const float*)d_in[7];
    const float* g2  = (const float*)d_in[8];
    const float* be2 = (const float*)d_in[9];
    const float* Wa  = (const float*)d_in[10];
    const float* ba  = (const float*)d_in[11];
    const int*   ei  = (const int*)d_in[12];

    float* ws    = (float*)d_ws;
    float* stats = ws;                       // 512 floats
    float* fwd   = ws + 512;                 // N*H
    float* bwd   = fwd + N_NODES * DIM;      // N*H
    int*   ip    = (int*)(bwd + N_NODES * DIM);
    int*   cnt   = ip;                       // 2N (col then row)
    int*   off   = ip + 2 * N_NODES;         // 2N (col then row)

    // edge lists live in d_out — dead before gemm1 writes h1p there
    int* e_col = (int*)d_out;                // E ints
    int* e_row = e_col + N_EDGES;            // E ints

    float* h1p = (float*)d_out;
    float* h2p = fwd;                        // fwd dead after gemm1
    float* out = (float*)d_out;

    k_init<<<(2 * N_NODES + 255) / 256, 256, 0, stream>>>(stats, cnt);
    k_count<<<(N_EDGES / 4 + 255) / 256, 256, 0, stream>>>(ei, cnt);
    k_scan<<<2, 1024, 0, stream>>>(cnt, off);
    k_fill<<<(N_EDGES / 4 + 255) / 256, 256, 0, stream>>>(ei, off, e_col, e_row);
    k_gather<<<(2 * N_NODES) / 4, 256, 0, stream>>>((const float4*)msg, e_col, off, fwd, bwd);
    k_gemm1<<<(N_NODES + 63) / 64, 256, 0, stream>>>(x, fwd, bwd, W1, b1, h1p, stats);
    k_gemm2<<<(N_NODES + 63) / 64, 256, 0, stream>>>(h1p, W2, b2, g1, be1, h2p, stats);
    k_final<<<(N_NODES + 3) / 4, 256, 0, stream>>>(h2p, stats, g2, be2, Wa, ba, out);
}

// Round 4
// 1044.803 us; speedup vs baseline: 8.0746x; 1.1380x over previous
//
#include <hip/hip_runtime.h>
#include <math.h>

#define N_NODES 50000
#define N_EDGES 1600000
#define DIM 128          // D == H == 128
#define EPS 1e-5f
#define SCAN_BLOCKS 49   // ceil(50000/1024)

// ---------------- A: zero stats + histograms ----------------
__global__ __launch_bounds__(256) void k_init(float* __restrict__ stats, int* __restrict__ cnt) {
    int i = blockIdx.x * 256 + threadIdx.x;
    if (i < 512) stats[i] = 0.0f;
    if (i < 2 * N_NODES) cnt[i] = 0;
}

// ---------------- B1: histogram of col (fwd) and row (bwd), 4 edges/thread ----------------
__global__ __launch_bounds__(256) void k_count(const int* __restrict__ ei, int* __restrict__ cnt) {
    int t = blockIdx.x * 256 + threadIdx.x;
    if (t >= N_EDGES / 4) return;
    int4 r4 = reinterpret_cast<const int4*>(ei)[t];
    int4 c4 = reinterpret_cast<const int4*>(ei + N_EDGES)[t];
    atomicAdd(&cnt[c4.x], 1); atomicAdd(&cnt[c4.y], 1);
    atomicAdd(&cnt[c4.z], 1); atomicAdd(&cnt[c4.w], 1);
    atomicAdd(&cnt[N_NODES + r4.x], 1); atomicAdd(&cnt[N_NODES + r4.y], 1);
    atomicAdd(&cnt[N_NODES + r4.z], 1); atomicAdd(&cnt[N_NODES + r4.w], 1);
}

// ---------------- B2a: per-block exclusive scan (1024 elems/block) ----------------
__global__ __launch_bounds__(256) void k_scan1(const int* __restrict__ cnt, int* __restrict__ off,
                                               int* __restrict__ bsums) {
    __shared__ int lds[256];
    const int a = (blockIdx.x >= SCAN_BLOCKS) ? 1 : 0;
    const int b = blockIdx.x - a * SCAN_BLOCKS;
    const int base = a * N_NODES + b * 1024;
    const int limit = a * N_NODES + N_NODES;
    const int t = threadIdx.x;
    const int i = base + t * 4;
    int4 v = make_int4(0, 0, 0, 0);
    if (i < limit) v = *reinterpret_cast<const int4*>(cnt + i);   // N_NODES % 4 == 0
    int s = v.x + v.y + v.z + v.w;
    lds[t] = s;
    __syncthreads();
    for (int d = 1; d < 256; d <<= 1) {
        int add = (t >= d) ? lds[t - d] : 0;
        __syncthreads();
        lds[t] += add;
        __syncthreads();
    }
    int excl = lds[t] - s;
    if (i < limit) {
        int4 o;
        o.x = excl;
        o.y = excl + v.x;
        o.z = excl + v.x + v.y;
        o.w = excl + v.x + v.y + v.z;
        *reinterpret_cast<int4*>(off + i) = o;
    }
    if (t == 255) bsums[blockIdx.x] = lds[255];
    if (blockIdx.x == 0 && t == 0) bsums[2 * SCAN_BLOCKS] = 0;   // unused pad
}

// ---------------- B2b: exclusive scan of block sums (both arrays, 1 block) ----------------
__global__ __launch_bounds__(128) void k_scan2(int* __restrict__ bsums) {
    __shared__ int lds[128];
    const int t = threadIdx.x;
    const int a = t >> 6;
    const int idx = t & 63;
    int v = (idx < SCAN_BLOCKS) ? bsums[a * SCAN_BLOCKS + idx] : 0;
    lds[t] = v;
    __syncthreads();
    for (int d = 1; d < 64; d <<= 1) {
        int add = (idx >= d) ? lds[t - d] : 0;
        __syncthreads();
        lds[t] += add;
        __syncthreads();
    }
    if (idx < SCAN_BLOCKS) bsums[a * SCAN_BLOCKS + idx] = lds[t] - v;   // exclusive
}

// ---------------- B2c: add block offsets ----------------
__global__ __launch_bounds__(256) void k_scan3(int* __restrict__ off, const int* __restrict__ bsums) {
    const int a = (blockIdx.x >= SCAN_BLOCKS) ? 1 : 0;
    const int b = blockIdx.x - a * SCAN_BLOCKS;
    const int base = a * N_NODES + b * 1024;
    const int limit = a * N_NODES + N_NODES;
    const int add = bsums[blockIdx.x];
    const int i = base + threadIdx.x * 4;
    if (i < limit) {
        int4 v = *reinterpret_cast<int4*>(off + i);
        v.x += add; v.y += add; v.z += add; v.w += add;
        *reinterpret_cast<int4*>(off + i) = v;
    }
}

// ---------------- B3: fill buckets (off becomes inclusive scan after this) ----------------
__global__ __launch_bounds__(256) void k_fill(const int* __restrict__ ei, int* __restrict__ off,
                                              int* __restrict__ e_col, int* __restrict__ e_row) {
    int t = blockIdx.x * 256 + threadIdx.x;
    if (t >= N_EDGES / 4) return;
    int4 r4 = reinterpret_cast<const int4*>(ei)[t];
    int4 c4 = reinterpret_cast<const int4*>(ei + N_EDGES)[t];
    int e = t * 4;
    e_col[atomicAdd(&off[c4.x], 1)] = e + 0;
    e_col[atomicAdd(&off[c4.y], 1)] = e + 1;
    e_col[atomicAdd(&off[c4.z], 1)] = e + 2;
    e_col[atomicAdd(&off[c4.w], 1)] = e + 3;
    e_row[atomicAdd(&off[N_NODES + r4.x], 1)] = e + 0;
    e_row[atomicAdd(&off[N_NODES + r4.y], 1)] = e + 1;
    e_row[atomicAdd(&off[N_NODES + r4.z], 1)] = e + 2;
    e_row[atomicAdd(&off[N_NODES + r4.w], 1)] = e + 3;
}

// ---------------- B4: gather-max. wave = (node,dir); float4 loads; 4 rows in flight ----------------
__global__ __launch_bounds__(256) void k_gather(const float4* __restrict__ msgv,
                                                const int* __restrict__ elist,  // e_col then e_row
                                                const int* __restrict__ off,    // inclusive, col then row
                                                float* __restrict__ fwd,
                                                float* __restrict__ bwd) {
    const int wid = blockIdx.x * 4 + (threadIdx.x >> 6);   // 0 .. 2N-1
    const int dir = (wid >= N_NODES);
    const int n = dir ? wid - N_NODES : wid;
    const int lane = threadIdx.x & 63;
    const int q = lane & 31;        // channel quad: channels q*4..q*4+3
    const int h = lane >> 5;        // row parity (half-wave)
    const int* eo = off + dir * N_NODES;
    const int* el = elist + (size_t)dir * N_EDGES;
    const int start = n ? eo[n - 1] : 0;
    const int end = eo[n];

    float4 acc = make_float4(-INFINITY, -INFINITY, -INFINITY, -INFINITY);
    int p = start + h;
    for (; p + 2 < end; p += 4) {
        int e0 = el[p], e1 = el[p + 2];
        float4 m0 = msgv[(size_t)e0 * 32 + q];
        float4 m1 = msgv[(size_t)e1 * 32 + q];
        m0.x = fmaxf(m0.x, m1.x); m0.y = fmaxf(m0.y, m1.y);
        m0.z = fmaxf(m0.z, m1.z); m0.w = fmaxf(m0.w, m1.w);
        acc.x = fmaxf(acc.x, m0.x); acc.y = fmaxf(acc.y, m0.y);
        acc.z = fmaxf(acc.z, m0.z); acc.w = fmaxf(acc.w, m0.w);
    }
    if (p < end) {
        float4 m = msgv[(size_t)el[p] * 32 + q];
        acc.x = fmaxf(acc.x, m.x); acc.y = fmaxf(acc.y, m.y);
        acc.z = fmaxf(acc.z, m.z); acc.w = fmaxf(acc.w, m.w);
    }
    acc.x = fmaxf(acc.x, __shfl_xor(acc.x, 32));
    acc.y = fmaxf(acc.y, __shfl_xor(acc.y, 32));
    acc.z = fmaxf(acc.z, __shfl_xor(acc.z, 32));
    acc.w = fmaxf(acc.w, __shfl_xor(acc.w, 32));

    if (h == 0) {
        if (start >= end) acc = make_float4(0.0f, 0.0f, 0.0f, 0.0f);  // empty segment -> 0
        float* dst = dir ? bwd : fwd;
        reinterpret_cast<float4*>(dst + n * DIM)[q] = acc;
    }
}

// ---------------- C: h1p = [x|fwd|bwd] @ W1 + b1, col stats ----------------
__global__ __launch_bounds__(256) void k_gemm1(const float* __restrict__ x,
                                               const float* __restrict__ fwd,
                                               const float* __restrict__ bwd,
                                               const float* __restrict__ W1,
                                               const float* __restrict__ b1,
                                               float* __restrict__ h1p,
                                               float* __restrict__ stats) {
    __shared__ float Wc[64 * 128];
    __shared__ float rows[64 * 64];
    const int tid = threadIdx.x;
    const int j = tid & 127;
    const int s = tid >> 7;
    const int n0 = blockIdx.x * 64;

    float acc[32];
#pragma unroll
    for (int i = 0; i < 32; ++i) acc[i] = 0.0f;

    for (int c = 0; c < 6; ++c) {
        const float* src = (c < 2) ? x : ((c < 4) ? fwd : bwd);
        const int koff = (c & 1) * 64;
        // stage W1 chunk [64][128] via float4
#pragma unroll
        for (int i = 0; i < 8; ++i) {
            int idx4 = tid + i * 256;
            reinterpret_cast<float4*>(Wc)[idx4] =
                reinterpret_cast<const float4*>(W1)[c * 2048 + idx4];
        }
        // stage 64 rows x 64 k via float4
#pragma unroll
        for (int i = 0; i < 4; ++i) {
            int idx4 = tid + i * 256;
            int r = idx4 >> 4, kq = idx4 & 15;
            int n = n0 + r;
            float4 v = make_float4(0.0f, 0.0f, 0.0f, 0.0f);
            if (n < N_NODES) v = reinterpret_cast<const float4*>(src + n * DIM + koff)[kq];
            reinterpret_cast<float4*>(rows)[idx4] = v;
        }
        __syncthreads();
#pragma unroll 2
        for (int k4 = 0; k4 < 16; ++k4) {
            float w0 = Wc[(k4 * 4 + 0) * 128 + j];
            float w1 = Wc[(k4 * 4 + 1) * 128 + j];
            float w2 = Wc[(k4 * 4 + 2) * 128 + j];
            float w3 = Wc[(k4 * 4 + 3) * 128 + j];
#pragma unroll
            for (int ri = 0; ri < 32; ++ri) {
                const float4 rv = *reinterpret_cast<const float4*>(&rows[(s + 2 * ri) * 64 + k4 * 4]);
                float a = acc[ri];
                a = fmaf(rv.x, w0, a);
                a = fmaf(rv.y, w1, a);
                a = fmaf(rv.z, w2, a);
                a = fmaf(rv.w, w3, a);
                acc[ri] = a;
            }
        }
        __syncthreads();
    }
    const float bj = b1[j];
    float sum = 0.0f, sq = 0.0f;
#pragma unroll
    for (int ri = 0; ri < 32; ++ri) {
        int n = n0 + s + 2 * ri;
        if (n < N_NODES) {
            float v = acc[ri] + bj;
            h1p[n * DIM + j] = v;
            sum += v;
            sq += v * v;
        }
    }
    atomicAdd(&stats[j], sum);
    atomicAdd(&stats[128 + j], sq);
}

// ---------------- D: h1 = relu(BN1(h1p)); h2p = h1 @ W2 + b2; col stats2 ----------------
__global__ __launch_bounds__(256) void k_gemm2(const float* __restrict__ h1p,
                                               const float* __restrict__ W2,
                                               const float* __restrict__ b2,
                                               const float* __restrict__ g1,
                                               const float* __restrict__ be1,
                                               float* __restrict__ h2p,
                                               float* __restrict__ stats) {
    __shared__ float Wc[64 * 128];
    __shared__ float rows[64 * 128];
    __shared__ float ssc[128], ssh[128];
    const int tid = threadIdx.x;
    const int j = tid & 127;
    const int s = tid >> 7;
    const int n0 = blockIdx.x * 64;

    if (tid < 128) {
        float mu = stats[tid] * (1.0f / N_NODES);
        float var = stats[128 + tid] * (1.0f / N_NODES) - mu * mu;
        float sc = rsqrtf(var + EPS) * g1[tid];
        ssc[tid] = sc;
        ssh[tid] = be1[tid] - mu * sc;
    }
    __syncthreads();
    // stage post-BN1+relu rows [64][128] via float4
#pragma unroll
    for (int i = 0; i < 8; ++i) {
        int idx4 = tid + i * 256;
        int r = idx4 >> 5, kq = idx4 & 31;
        int n = n0 + r;
        float4 v = make_float4(0.0f, 0.0f, 0.0f, 0.0f);
        if (n < N_NODES) {
            v = reinterpret_cast<const float4*>(h1p + n * DIM)[kq];
            float4 sc4 = reinterpret_cast<const float4*>(ssc)[kq];
            float4 sh4 = reinterpret_cast<const float4*>(ssh)[kq];
            v.x = fmaxf(v.x * sc4.x + sh4.x, 0.0f);
            v.y = fmaxf(v.y * sc4.y + sh4.y, 0.0f);
            v.z = fmaxf(v.z * sc4.z + sh4.z, 0.0f);
            v.w = fmaxf(v.w * sc4.w + sh4.w, 0.0f);
        }
        reinterpret_cast<float4*>(rows)[idx4] = v;
    }
    float acc[32];
#pragma unroll
    for (int i = 0; i < 32; ++i) acc[i] = 0.0f;

    for (int c = 0; c < 2; ++c) {
        __syncthreads();
#pragma unroll
        for (int i = 0; i < 8; ++i) {
            int idx4 = tid + i * 256;
            reinterpret_cast<float4*>(Wc)[idx4] =
                reinterpret_cast<const float4*>(W2)[c * 2048 + idx4];
        }
        __syncthreads();
#pragma unroll 2
        for (int k4 = 0; k4 < 16; ++k4) {
            float w0 = Wc[(k4 * 4 + 0) * 128 + j];
            float w1 = Wc[(k4 * 4 + 1) * 128 + j];
            float w2 = Wc[(k4 * 4 + 2) * 128 + j];
            float w3 = Wc[(k4 * 4 + 3) * 128 + j];
#pragma unroll
            for (int ri = 0; ri < 32; ++ri) {
                const float4 rv = *reinterpret_cast<const float4*>(
                    &rows[(s + 2 * ri) * 128 + c * 64 + k4 * 4]);
                float a = acc[ri];
                a = fmaf(rv.x, w0, a);
                a = fmaf(rv.y, w1, a);
                a = fmaf(rv.z, w2, a);
                a = fmaf(rv.w, w3, a);
                acc[ri] = a;
            }
        }
    }
    const float bj = b2[j];
    float sum = 0.0f, sq = 0.0f;
#pragma unroll
    for (int ri = 0; ri < 32; ++ri) {
        int n = n0 + s + 2 * ri;
        if (n < N_NODES) {
            float v = acc[ri] + bj;
            h2p[n * DIM + j] = v;
            sum += v;
            sq += v * v;
        }
    }
    atomicAdd(&stats[256 + j], sum);
    atomicAdd(&stats[384 + j], sq);
}

// ---------------- E: h = relu(BN2(h2p)) -> out; att = sigmoid(h @ Wa + ba) ----------------
__global__ __launch_bounds__(256) void k_final(const float* __restrict__ h2p,
                                               const float* __restrict__ stats,
                                               const float* __restrict__ g2,
                                               const float* __restrict__ be2,
                                               const float* __restrict__ Wa,
                                               const float* __restrict__ ba,
                                               float* __restrict__ out) {
    const int lane = threadIdx.x & 63;
    const int wv = threadIdx.x >> 6;
    const int n = blockIdx.x * 4 + wv;
    if (n >= N_NODES) return;
    const int j0 = lane, j1 = lane + 64;

    float mu0 = stats[256 + j0] * (1.0f / N_NODES);
    float var0 = stats[384 + j0] * (1.0f / N_NODES) - mu0 * mu0;
    float sc0 = rsqrtf(var0 + EPS) * g2[j0];
    float sh0 = be2[j0] - mu0 * sc0;
    float mu1 = stats[256 + j1] * (1.0f / N_NODES);
    float var1 = stats[384 + j1] * (1.0f / N_NODES) - mu1 * mu1;
    float sc1 = rsqrtf(var1 + EPS) * g2[j1];
    float sh1 = be2[j1] - mu1 * sc1;

    float v0 = fmaxf(h2p[n * DIM + j0] * sc0 + sh0, 0.0f);
    float v1 = fmaxf(h2p[n * DIM + j1] * sc1 + sh1, 0.0f);
    out[n * DIM + j0] = v0;
    out[n * DIM + j1] = v1;

    float p = v0 * Wa[j0] + v1 * Wa[j1];
#pragma unroll
    for (int off = 32; off > 0; off >>= 1) p += __shfl_down(p, off);
    if (lane == 0) out[N_NODES * DIM + n] = 1.0f / (1.0f + expf(-(p + ba[0])));
}

extern "C" void kernel_launch(void* const* d_in, const int* in_sizes, int n_in,
                              void* d_out, int out_size, void* d_ws, size_t ws_size,
                              hipStream_t stream) {
    const float* x   = (const float*)d_in[0];
    const float* msg = (const float*)d_in[1];
    const float* W1  = (const float*)d_in[2];
    const float* b1  = (const float*)d_in[3];
    const float* g1  = (const float*)d_in[4];
    const float* be1 = (const float*)d_in[5];
    const float* W2  = (const float*)d_in[6];
    const float* b2  = (const float*)d_in[7];
    const float* g2  = (const float*)d_in[8];
    const float* be2 = (const float*)d_in[9];
    const float* Wa  = (const float*)d_in[10];
    const float* ba  = (const float*)d_in[11];
    const int*   ei  = (const int*)d_in[12];

    float* ws    = (float*)d_ws;
    float* stats = ws;                       // 512 floats
    float* fwd   = ws + 512;                 // N*H
    float* bwd   = fwd + N_NODES * DIM;      // N*H
    int*   ip    = (int*)(bwd + N_NODES * DIM);
    int*   cnt   = ip;                       // 2N (col then row)
    int*   off   = ip + 2 * N_NODES;         // 2N (col then row)
    int*   bsums = ip + 4 * N_NODES;         // 2*SCAN_BLOCKS + 1

    // edge lists live in d_out — dead before gemm1 writes h1p there
    int* e_col = (int*)d_out;                // E ints
    int* e_row = e_col + N_EDGES;            // E ints

    float* h1p = (float*)d_out;
    float* h2p = fwd;                        // fwd dead after gemm1
    float* out = (float*)d_out;

    k_init<<<(2 * N_NODES + 255) / 256, 256, 0, stream>>>(stats, cnt);
    k_count<<<(N_EDGES / 4 + 255) / 256, 256, 0, stream>>>(ei, cnt);
    k_scan1<<<2 * SCAN_BLOCKS, 256, 0, stream>>>(cnt, off, bsums);
    k_scan2<<<1, 128, 0, stream>>>(bsums);
    k_scan3<<<2 * SCAN_BLOCKS, 256, 0, stream>>>(off, bsums);
    k_fill<<<(N_EDGES / 4 + 255) / 256, 256, 0, stream>>>(ei, off, e_col, e_row);
    k_gather<<<(2 * N_NODES) / 4, 256, 0, stream>>>((const float4*)msg, e_col, off, fwd, bwd);
    k_gemm1<<<(N_NODES + 63) / 64, 256, 0, stream>>>(x, fwd, bwd, W1, b1, h1p, stats);
    k_gemm2<<<(N_NODES + 63) / 64, 256, 0, stream>>>(h1p, W2, b2, g1, be1, h2p, stats);
    k_final<<<(N_NODES + 3) / 4, 256, 0, stream>>>(h2p, stats, g2, be2, Wa, ba, out);
}

// Round 5
// 752.355 us; speedup vs baseline: 11.2133x; 1.3887x over previous
//
#include <hip/hip_runtime.h>
#include <math.h>

#define N_NODES 50000
#define N_EDGES 1600000
#define DIM 128          // D == H == 128
#define EPS 1e-5f
#define CAP 128          // bucket capacity; P(Poisson(32) > 128) ~ 1e-35 per bucket

__device__ __forceinline__ float4 f4max(float4 a, float4 b) {
    return make_float4(fmaxf(a.x, b.x), fmaxf(a.y, b.y), fmaxf(a.z, b.z), fmaxf(a.w, b.w));
}

// ---------------- A: zero stats + bucket counters ----------------
__global__ __launch_bounds__(256) void k_init(float* __restrict__ stats, int* __restrict__ cnt) {
    int i = blockIdx.x * 256 + threadIdx.x;
    if (i < 512) stats[i] = 0.0f;
    if (i < 2 * N_NODES) cnt[i] = 0;
}

// ---------------- B: bucket edges by col (fwd) and row (bwd), fixed stride CAP ----------------
__global__ __launch_bounds__(256) void k_bucket(const int* __restrict__ ei, int* __restrict__ cnt,
                                                int* __restrict__ slots) {
    int t = blockIdx.x * 256 + threadIdx.x;
    if (t >= N_EDGES / 4) return;
    int4 r4 = reinterpret_cast<const int4*>(ei)[t];
    int4 c4 = reinterpret_cast<const int4*>(ei + N_EDGES)[t];
    int e = t * 4;
    slots[c4.x * CAP + atomicAdd(&cnt[c4.x], 1)] = e + 0;
    slots[c4.y * CAP + atomicAdd(&cnt[c4.y], 1)] = e + 1;
    slots[c4.z * CAP + atomicAdd(&cnt[c4.z], 1)] = e + 2;
    slots[c4.w * CAP + atomicAdd(&cnt[c4.w], 1)] = e + 3;
    slots[(N_NODES + r4.x) * CAP + atomicAdd(&cnt[N_NODES + r4.x], 1)] = e + 0;
    slots[(N_NODES + r4.y) * CAP + atomicAdd(&cnt[N_NODES + r4.y], 1)] = e + 1;
    slots[(N_NODES + r4.z) * CAP + atomicAdd(&cnt[N_NODES + r4.z], 1)] = e + 2;
    slots[(N_NODES + r4.w) * CAP + atomicAdd(&cnt[N_NODES + r4.w], 1)] = e + 3;
}

// ---------------- C: gather-max. wave = (node,dir); 4 rows in flight per half-wave ----------------
__global__ __launch_bounds__(256) void k_gather(const float4* __restrict__ msgv,
                                                const int* __restrict__ slots,
                                                const int* __restrict__ cnt,
                                                float* __restrict__ fwd,
                                                float* __restrict__ bwd) {
    const int wid = blockIdx.x * 4 + (threadIdx.x >> 6);   // 0 .. 2N-1
    const int dir = (wid >= N_NODES);
    const int n = dir ? wid - N_NODES : wid;
    const int lane = threadIdx.x & 63;
    const int q = lane & 31;        // channel quad: channels q*4..q*4+3
    const int h = lane >> 5;        // half-wave id
    const int c = cnt[dir * N_NODES + n];
    const int* el = slots + (size_t)(dir * N_NODES + n) * CAP;

    float4 acc = make_float4(-INFINITY, -INFINITY, -INFINITY, -INFINITY);
    const int nfull = c >> 2;
    // full groups of 4, alternating halves (el 16B-aligned: base is CAP-int aligned)
    for (int g = h; g < nfull; g += 2) {
        int4 e4 = *reinterpret_cast<const int4*>(el + g * 4);   // broadcast within half-wave
        float4 m0 = msgv[(size_t)e4.x * 32 + q];
        float4 m1 = msgv[(size_t)e4.y * 32 + q];
        float4 m2 = msgv[(size_t)e4.z * 32 + q];
        float4 m3 = msgv[(size_t)e4.w * 32 + q];
        acc = f4max(acc, f4max(f4max(m0, m1), f4max(m2, m3)));
    }
    // tail (c & 3 edges), owned by half (nfull & 1)
    if (h == (nfull & 1)) {
        for (int p = nfull * 4; p < c; ++p) {
            acc = f4max(acc, msgv[(size_t)el[p] * 32 + q]);
        }
    }
    acc.x = fmaxf(acc.x, __shfl_xor(acc.x, 32));
    acc.y = fmaxf(acc.y, __shfl_xor(acc.y, 32));
    acc.z = fmaxf(acc.z, __shfl_xor(acc.z, 32));
    acc.w = fmaxf(acc.w, __shfl_xor(acc.w, 32));

    if (h == 0) {
        if (c == 0) acc = make_float4(0.0f, 0.0f, 0.0f, 0.0f);  // empty segment -> 0
        float* dst = dir ? bwd : fwd;
        reinterpret_cast<float4*>(dst + n * DIM)[q] = acc;
    }
}

// ---------------- D: h1p = [x|fwd|bwd] @ W1 + b1, col stats ----------------
// block 256 = (jq 0..31, rg 0..7); thread tile = 8 rows x 4 cols; 64 rows/block.
__global__ __launch_bounds__(256) void k_gemm1(const float* __restrict__ x,
                                               const float* __restrict__ fwd,
                                               const float* __restrict__ bwd,
                                               const float* __restrict__ W1,
                                               const float* __restrict__ b1,
                                               float* __restrict__ h1p,
                                               float* __restrict__ stats) {
    __shared__ float Wc[64 * 128];
    __shared__ float rows[64 * 64];
    __shared__ float red[256 * 4];
    const int tid = threadIdx.x;
    const int jq = tid & 31;
    const int rg = tid >> 5;
    const int n0 = blockIdx.x * 64;

    float4 acc[8];
#pragma unroll
    for (int i = 0; i < 8; ++i) acc[i] = make_float4(0.0f, 0.0f, 0.0f, 0.0f);

    for (int c = 0; c < 6; ++c) {
        const float* src = (c < 2) ? x : ((c < 4) ? fwd : bwd);
        const int koff = (c & 1) * 64;
#pragma unroll
        for (int i = 0; i < 8; ++i) {
            int idx4 = tid + i * 256;
            reinterpret_cast<float4*>(Wc)[idx4] =
                reinterpret_cast<const float4*>(W1)[c * 2048 + idx4];
        }
#pragma unroll
        for (int i = 0; i < 4; ++i) {
            int idx4 = tid + i * 256;
            int r = idx4 >> 4, kq = idx4 & 15;
            int n = n0 + r;
            float4 v = make_float4(0.0f, 0.0f, 0.0f, 0.0f);
            if (n < N_NODES) v = reinterpret_cast<const float4*>(src + n * DIM + koff)[kq];
            reinterpret_cast<float4*>(rows)[idx4] = v;
        }
        __syncthreads();
#pragma unroll 4
        for (int k4 = 0; k4 < 16; ++k4) {
            const float4 w0 = reinterpret_cast<const float4*>(Wc)[(k4 * 4 + 0) * 32 + jq];
            const float4 w1 = reinterpret_cast<const float4*>(Wc)[(k4 * 4 + 1) * 32 + jq];
            const float4 w2 = reinterpret_cast<const float4*>(Wc)[(k4 * 4 + 2) * 32 + jq];
            const float4 w3 = reinterpret_cast<const float4*>(Wc)[(k4 * 4 + 3) * 32 + jq];
#pragma unroll
            for (int i = 0; i < 8; ++i) {
                const float4 r = reinterpret_cast<const float4*>(rows)[(rg * 8 + i) * 16 + k4];
                float4 a = acc[i];
                a.x = fmaf(r.x, w0.x, fmaf(r.y, w1.x, fmaf(r.z, w2.x, fmaf(r.w, w3.x, a.x))));
                a.y = fmaf(r.x, w0.y, fmaf(r.y, w1.y, fmaf(r.z, w2.y, fmaf(r.w, w3.y, a.y))));
                a.z = fmaf(r.x, w0.z, fmaf(r.y, w1.z, fmaf(r.z, w2.z, fmaf(r.w, w3.z, a.z))));
                a.w = fmaf(r.x, w0.w, fmaf(r.y, w1.w, fmaf(r.z, w2.w, fmaf(r.w, w3.w, a.w))));
                acc[i] = a;
            }
        }
        __syncthreads();
    }
    const float4 bj = reinterpret_cast<const float4*>(b1)[jq];
    float4 sum = make_float4(0.0f, 0.0f, 0.0f, 0.0f);
    float4 sq = make_float4(0.0f, 0.0f, 0.0f, 0.0f);
#pragma unroll
    for (int i = 0; i < 8; ++i) {
        int n = n0 + rg * 8 + i;
        if (n < N_NODES) {
            float4 v = acc[i];
            v.x += bj.x; v.y += bj.y; v.z += bj.z; v.w += bj.w;
            reinterpret_cast<float4*>(h1p + n * DIM)[jq] = v;
            sum.x += v.x; sum.y += v.y; sum.z += v.z; sum.w += v.w;
            sq.x += v.x * v.x; sq.y += v.y * v.y; sq.z += v.z * v.z; sq.w += v.w * v.w;
        }
    }
    // LDS reduce over rg, then one atomic per column
    reinterpret_cast<float4*>(red)[tid] = sum;
    __syncthreads();
    if (tid < 128) {
        int jqq = tid >> 2, comp = tid & 3;
        float s = 0.0f;
#pragma unroll
        for (int g = 0; g < 8; ++g) s += red[(g * 32 + jqq) * 4 + comp];
        atomicAdd(&stats[tid], s);
    }
    __syncthreads();
    reinterpret_cast<float4*>(red)[tid] = sq;
    __syncthreads();
    if (tid < 128) {
        int jqq = tid >> 2, comp = tid & 3;
        float s = 0.0f;
#pragma unroll
        for (int g = 0; g < 8; ++g) s += red[(g * 32 + jqq) * 4 + comp];
        atomicAdd(&stats[128 + tid], s);
    }
}

// ---------------- E: h1 = relu(BN1(h1p)); h2p = h1 @ W2 + b2; col stats2 ----------------
__global__ __launch_bounds__(256) void k_gemm2(const float* __restrict__ h1p,
                                               const float* __restrict__ W2,
                                               const float* __restrict__ b2,
                                               const float* __restrict__ g1,
                                               const float* __restrict__ be1,
                                               float* __restrict__ h2p,
                                               float* __restrict__ stats) {
    __shared__ float Wc[64 * 128];
    __shared__ float rows[64 * 128];
    __shared__ float ssc[128], ssh[128];
    __shared__ float red[256 * 4];
    const int tid = threadIdx.x;
    const int jq = tid & 31;
    const int rg = tid >> 5;
    const int n0 = blockIdx.x * 64;

    if (tid < 128) {
        float mu = stats[tid] * (1.0f / N_NODES);
        float var = stats[128 + tid] * (1.0f / N_NODES) - mu * mu;
        float sc = rsqrtf(var + EPS) * g1[tid];
        ssc[tid] = sc;
        ssh[tid] = be1[tid] - mu * sc;
    }
    __syncthreads();
#pragma unroll
    for (int i = 0; i < 8; ++i) {
        int idx4 = tid + i * 256;
        int r = idx4 >> 5, kq = idx4 & 31;
        int n = n0 + r;
        float4 v = make_float4(0.0f, 0.0f, 0.0f, 0.0f);
        if (n < N_NODES) {
            v = reinterpret_cast<const float4*>(h1p + n * DIM)[kq];
            float4 sc4 = reinterpret_cast<const float4*>(ssc)[kq];
            float4 sh4 = reinterpret_cast<const float4*>(ssh)[kq];
            v.x = fmaxf(v.x * sc4.x + sh4.x, 0.0f);
            v.y = fmaxf(v.y * sc4.y + sh4.y, 0.0f);
            v.z = fmaxf(v.z * sc4.z + sh4.z, 0.0f);
            v.w = fmaxf(v.w * sc4.w + sh4.w, 0.0f);
        }
        reinterpret_cast<float4*>(rows)[idx4] = v;
    }
    float4 acc[8];
#pragma unroll
    for (int i = 0; i < 8; ++i) acc[i] = make_float4(0.0f, 0.0f, 0.0f, 0.0f);

    for (int c = 0; c < 2; ++c) {
        __syncthreads();
#pragma unroll
        for (int i = 0; i < 8; ++i) {
            int idx4 = tid + i * 256;
            reinterpret_cast<float4*>(Wc)[idx4] =
                reinterpret_cast<const float4*>(W2)[c * 2048 + idx4];
        }
        __syncthreads();
#pragma unroll 4
        for (int k4 = 0; k4 < 16; ++k4) {
            const float4 w0 = reinterpret_cast<const float4*>(Wc)[(k4 * 4 + 0) * 32 + jq];
            const float4 w1 = reinterpret_cast<const float4*>(Wc)[(k4 * 4 + 1) * 32 + jq];
            const float4 w2 = reinterpret_cast<const float4*>(Wc)[(k4 * 4 + 2) * 32 + jq];
            const float4 w3 = reinterpret_cast<const float4*>(Wc)[(k4 * 4 + 3) * 32 + jq];
#pragma unroll
            for (int i = 0; i < 8; ++i) {
                const float4 r = reinterpret_cast<const float4*>(rows)[(rg * 8 + i) * 32 + c * 16 + k4];
                float4 a = acc[i];
                a.x = fmaf(r.x, w0.x, fmaf(r.y, w1.x, fmaf(r.z, w2.x, fmaf(r.w, w3.x, a.x))));
                a.y = fmaf(r.x, w0.y, fmaf(r.y, w1.y, fmaf(r.z, w2.y, fmaf(r.w, w3.y, a.y))));
                a.z = fmaf(r.x, w0.z, fmaf(r.y, w1.z, fmaf(r.z, w2.z, fmaf(r.w, w3.z, a.z))));
                a.w = fmaf(r.x, w0.w, fmaf(r.y, w1.w, fmaf(r.z, w2.w, fmaf(r.w, w3.w, a.w))));
                acc[i] = a;
            }
        }
    }
    const float4 bj = reinterpret_cast<const float4*>(b2)[jq];
    float4 sum = make_float4(0.0f, 0.0f, 0.0f, 0.0f);
    float4 sq = make_float4(0.0f, 0.0f, 0.0f, 0.0f);
#pragma unroll
    for (int i = 0; i < 8; ++i) {
        int n = n0 + rg * 8 + i;
        if (n < N_NODES) {
            float4 v = acc[i];
            v.x += bj.x; v.y += bj.y; v.z += bj.z; v.w += bj.w;
            reinterpret_cast<float4*>(h2p + n * DIM)[jq] = v;
            sum.x += v.x; sum.y += v.y; sum.z += v.z; sum.w += v.w;
            sq.x += v.x * v.x; sq.y += v.y * v.y; sq.z += v.z * v.z; sq.w += v.w * v.w;
        }
    }
    reinterpret_cast<float4*>(red)[tid] = sum;
    __syncthreads();
    if (tid < 128) {
        int jqq = tid >> 2, comp = tid & 3;
        float s = 0.0f;
#pragma unroll
        for (int g = 0; g < 8; ++g) s += red[(g * 32 + jqq) * 4 + comp];
        atomicAdd(&stats[256 + tid], s);
    }
    __syncthreads();
    reinterpret_cast<float4*>(red)[tid] = sq;
    __syncthreads();
    if (tid < 128) {
        int jqq = tid >> 2, comp = tid & 3;
        float s = 0.0f;
#pragma unroll
        for (int g = 0; g < 8; ++g) s += red[(g * 32 + jqq) * 4 + comp];
        atomicAdd(&stats[384 + tid], s);
    }
}

// ---------------- F: h = relu(BN2(h2p)) -> out; att = sigmoid(h @ Wa + ba) ----------------
__global__ __launch_bounds__(256) void k_final(const float* __restrict__ h2p,
                                               const float* __restrict__ stats,
                                               const float* __restrict__ g2,
                                               const float* __restrict__ be2,
                                               const float* __restrict__ Wa,
                                               const float* __restrict__ ba,
                                               float* __restrict__ out) {
    const int lane = threadIdx.x & 63;
    const int wv = threadIdx.x >> 6;
    const int n = blockIdx.x * 4 + wv;
    if (n >= N_NODES) return;
    const int j0 = lane, j1 = lane + 64;

    float mu0 = stats[256 + j0] * (1.0f / N_NODES);
    float var0 = stats[384 + j0] * (1.0f / N_NODES) - mu0 * mu0;
    float sc0 = rsqrtf(var0 + EPS) * g2[j0];
    float sh0 = be2[j0] - mu0 * sc0;
    float mu1 = stats[256 + j1] * (1.0f / N_NODES);
    float var1 = stats[384 + j1] * (1.0f / N_NODES) - mu1 * mu1;
    float sc1 = rsqrtf(var1 + EPS) * g2[j1];
    float sh1 = be2[j1] - mu1 * sc1;

    float v0 = fmaxf(h2p[n * DIM + j0] * sc0 + sh0, 0.0f);
    float v1 = fmaxf(h2p[n * DIM + j1] * sc1 + sh1, 0.0f);
    out[n * DIM + j0] = v0;
    out[n * DIM + j1] = v1;

    float p = v0 * Wa[j0] + v1 * Wa[j1];
#pragma unroll
    for (int off = 32; off > 0; off >>= 1) p += __shfl_down(p, off);
    if (lane == 0) out[N_NODES * DIM + n] = 1.0f / (1.0f + expf(-(p + ba[0])));
}

extern "C" void kernel_launch(void* const* d_in, const int* in_sizes, int n_in,
                              void* d_out, int out_size, void* d_ws, size_t ws_size,
                              hipStream_t stream) {
    const float* x   = (const float*)d_in[0];
    const float* msg = (const float*)d_in[1];
    const float* W1  = (const float*)d_in[2];
    const float* b1  = (const float*)d_in[3];
    const float* g1  = (const float*)d_in[4];
    const float* be1 = (const float*)d_in[5];
    const float* W2  = (const float*)d_in[6];
    const float* b2  = (const float*)d_in[7];
    const float* g2  = (const float*)d_in[8];
    const float* be2 = (const float*)d_in[9];
    const float* Wa  = (const float*)d_in[10];
    const float* ba  = (const float*)d_in[11];
    const int*   ei  = (const int*)d_in[12];

    float* ws    = (float*)d_ws;
    float* stats = ws;                           // 512 floats
    float* fwd   = ws + 512;                     // N*H
    float* bwd   = fwd + N_NODES * DIM;          // N*H
    int*   cnt   = (int*)(bwd + N_NODES * DIM);  // 2N (col then row)
    int*   slots = cnt + 2 * N_NODES;            // 2N * CAP  (51.2 MB)

    float* h1p = (float*)d_out;                  // scratch in out buffer
    float* h2p = fwd;                            // fwd dead after gemm1
    float* out = (float*)d_out;

    k_init<<<(2 * N_NODES + 255) / 256, 256, 0, stream>>>(stats, cnt);
    k_bucket<<<(N_EDGES / 4 + 255) / 256, 256, 0, stream>>>(ei, cnt, slots);
    k_gather<<<(2 * N_NODES) / 4, 256, 0, stream>>>((const float4*)msg, slots, cnt, fwd, bwd);
    k_gemm1<<<(N_NODES + 63) / 64, 256, 0, stream>>>(x, fwd, bwd, W1, b1, h1p, stats);
    k_gemm2<<<(N_NODES + 63) / 64, 256, 0, stream>>>(h1p, W2, b2, g1, be1, h2p, stats);
    k_final<<<(N_NODES + 3) / 4, 256, 0, stream>>>(h2p, stats, g2, be2, Wa, ba, out);
}

// Round 6
// 684.540 us; speedup vs baseline: 12.3242x; 1.0991x over previous
//
#include <hip/hip_runtime.h>
#include <math.h>

#define N_NODES 50000
#define N_EDGES 1600000
#define DIM 128          // D == H == 128
#define EPS 1e-5f
#define CAP 128          // bucket capacity; P(Poisson(32) > 128) ~ 1e-35 per bucket

typedef short bf16x8 __attribute__((ext_vector_type(8)));
typedef float f32x4 __attribute__((ext_vector_type(4)));
typedef unsigned short ushort_t;

__device__ __forceinline__ float4 f4max(float4 a, float4 b) {
    return make_float4(fmaxf(a.x, b.x), fmaxf(a.y, b.y), fmaxf(a.z, b.z), fmaxf(a.w, b.w));
}

// fp32 -> bf16 with round-to-nearest-even (matches HW cvt for normals)
__device__ __forceinline__ ushort_t f2bf(float f) {
    unsigned int u = __float_as_uint(f);
    return (ushort_t)((u + 0x7FFFu + ((u >> 16) & 1u)) >> 16);
}

// ---------------- A: zero stats + bucket counters ----------------
__global__ __launch_bounds__(256) void k_init(float* __restrict__ stats, int* __restrict__ cnt) {
    int i = blockIdx.x * 256 + threadIdx.x;
    if (i < 512) stats[i] = 0.0f;
    if (i < 2 * N_NODES) cnt[i] = 0;
}

// ---------------- A2: W1 -> W1t bf16 [128j][384k]; W2 -> W2t bf16 [128j][128k] ----------------
__global__ __launch_bounds__(256) void k_prep(const float* __restrict__ W1, const float* __restrict__ W2,
                                              ushort_t* __restrict__ W1t, ushort_t* __restrict__ W2t) {
    int gid = blockIdx.x * 256 + threadIdx.x;
    if (gid < 128 * 384) {
        int j = gid / 384, k = gid % 384;
        W1t[gid] = f2bf(W1[k * 128 + j]);
    } else {
        int g2 = gid - 128 * 384;
        if (g2 < 128 * 128) {
            int j = g2 / 128, k = g2 % 128;
            W2t[g2] = f2bf(W2[k * 128 + j]);
        }
    }
}

// ---------------- B: bucket edges by col (fwd) and row (bwd), fixed stride CAP ----------------
__global__ __launch_bounds__(256) void k_bucket(const int* __restrict__ ei, int* __restrict__ cnt,
                                                int* __restrict__ slots) {
    int t = blockIdx.x * 256 + threadIdx.x;
    if (t >= N_EDGES / 4) return;
    int4 r4 = reinterpret_cast<const int4*>(ei)[t];
    int4 c4 = reinterpret_cast<const int4*>(ei + N_EDGES)[t];
    int e = t * 4;
    slots[c4.x * CAP + atomicAdd(&cnt[c4.x], 1)] = e + 0;
    slots[c4.y * CAP + atomicAdd(&cnt[c4.y], 1)] = e + 1;
    slots[c4.z * CAP + atomicAdd(&cnt[c4.z], 1)] = e + 2;
    slots[c4.w * CAP + atomicAdd(&cnt[c4.w], 1)] = e + 3;
    slots[(N_NODES + r4.x) * CAP + atomicAdd(&cnt[N_NODES + r4.x], 1)] = e + 0;
    slots[(N_NODES + r4.y) * CAP + atomicAdd(&cnt[N_NODES + r4.y], 1)] = e + 1;
    slots[(N_NODES + r4.z) * CAP + atomicAdd(&cnt[N_NODES + r4.z], 1)] = e + 2;
    slots[(N_NODES + r4.w) * CAP + atomicAdd(&cnt[N_NODES + r4.w], 1)] = e + 3;
}

// ---------------- C: gather-max. wave = (node,dir); 4 rows in flight per half-wave ----------------
__global__ __launch_bounds__(256) void k_gather(const float4* __restrict__ msgv,
                                                const int* __restrict__ slots,
                                                const int* __restrict__ cnt,
                                                float* __restrict__ fwd,
                                                float* __restrict__ bwd) {
    const int wid = blockIdx.x * 4 + (threadIdx.x >> 6);   // 0 .. 2N-1
    const int dir = (wid >= N_NODES);
    const int n = dir ? wid - N_NODES : wid;
    const int lane = threadIdx.x & 63;
    const int q = lane & 31;        // channel quad
    const int h = lane >> 5;        // half-wave id
    const int c = cnt[dir * N_NODES + n];
    const int* el = slots + (size_t)(dir * N_NODES + n) * CAP;

    float4 acc = make_float4(-INFINITY, -INFINITY, -INFINITY, -INFINITY);
    const int nfull = c >> 2;
    for (int g = h; g < nfull; g += 2) {
        int4 e4 = *reinterpret_cast<const int4*>(el + g * 4);
        float4 m0 = msgv[(size_t)e4.x * 32 + q];
        float4 m1 = msgv[(size_t)e4.y * 32 + q];
        float4 m2 = msgv[(size_t)e4.z * 32 + q];
        float4 m3 = msgv[(size_t)e4.w * 32 + q];
        acc = f4max(acc, f4max(f4max(m0, m1), f4max(m2, m3)));
    }
    if (h == (nfull & 1)) {
        for (int p = nfull * 4; p < c; ++p) {
            acc = f4max(acc, msgv[(size_t)el[p] * 32 + q]);
        }
    }
    acc.x = fmaxf(acc.x, __shfl_xor(acc.x, 32));
    acc.y = fmaxf(acc.y, __shfl_xor(acc.y, 32));
    acc.z = fmaxf(acc.z, __shfl_xor(acc.z, 32));
    acc.w = fmaxf(acc.w, __shfl_xor(acc.w, 32));

    if (h == 0) {
        if (c == 0) acc = make_float4(0.0f, 0.0f, 0.0f, 0.0f);  // empty segment -> 0
        float* dst = dir ? bwd : fwd;
        reinterpret_cast<float4*>(dst + n * DIM)[q] = acc;
    }
}

// ======== MFMA GEMM core (64 rows x 128 cols per block, 4 waves, 16x16x32 bf16) ========
// LDS tiles XOR-swizzled: byte ^= ((row&7)<<4) to break 128B-row bank conflicts.

// ---------------- D: h1p = [x|fwd|bwd] @ W1 + b1, col stats ----------------
__global__ __launch_bounds__(256) void k_gemm1(const float* __restrict__ x,
                                               const float* __restrict__ fwd,
                                               const float* __restrict__ bwd,
                                               const ushort_t* __restrict__ W1t,
                                               const float* __restrict__ b1,
                                               float* __restrict__ h1p,
                                               float* __restrict__ stats) {
    __shared__ uint4 rowsA4[512];      // 64 rows x 64 k bf16 (8 KB), swizzled
    __shared__ uint4 Wt4[1024];        // 128 j x 64 k bf16 (16 KB), swizzled
    __shared__ float bias[128];
    __shared__ float s_sum[128], s_sq[128];
    char* rowsA = (char*)rowsA4;
    char* Wt = (char*)Wt4;

    const int tid = threadIdx.x;
    const int wid = tid >> 6;
    const int lane = tid & 63;
    const int ln15 = lane & 15;
    const int kb16 = (lane >> 4) * 16;          // byte offset of this lane-group's k8
    const int n0 = blockIdx.x * 64;
    const int rA = wid * 16 + ln15;             // A-row this lane reads
    const int rsw = (rA & 7) << 4;

    if (tid < 128) { bias[tid] = b1[tid]; s_sum[tid] = 0.0f; s_sq[tid] = 0.0f; }

    f32x4 acc[8];
#pragma unroll
    for (int i = 0; i < 8; ++i) acc[i] = (f32x4){0.0f, 0.0f, 0.0f, 0.0f};

    for (int c = 0; c < 6; ++c) {
        const float* src = (c < 2) ? x : ((c < 4) ? fwd : bwd);
        const int koff = (c & 1) * 64;
        __syncthreads();
        // stage rows: 64 x 64 bf16; task g -> (r = g>>3, k8 = g&7)
#pragma unroll
        for (int i = 0; i < 2; ++i) {
            int g = tid + i * 256;
            int r = g >> 3, k8 = g & 7;
            int n = n0 + r;
            float4 v0 = make_float4(0.f, 0.f, 0.f, 0.f), v1 = v0;
            if (n < N_NODES) {
                const float4* p = reinterpret_cast<const float4*>(src + n * DIM + koff + k8 * 8);
                v0 = p[0]; v1 = p[1];
            }
            ushort_t pk[8] = {f2bf(v0.x), f2bf(v0.y), f2bf(v0.z), f2bf(v0.w),
                              f2bf(v1.x), f2bf(v1.y), f2bf(v1.z), f2bf(v1.w)};
            *(uint4*)(rowsA + ((r * 128 + k8 * 16) ^ ((r & 7) << 4))) = *(const uint4*)pk;
        }
        // stage W1t chunk: 128 j x 64 k bf16 (pre-converted, contiguous in k)
#pragma unroll
        for (int i = 0; i < 4; ++i) {
            int g = tid + i * 256;
            int j = g >> 3, k8 = g & 7;
            uint4 w = *reinterpret_cast<const uint4*>(W1t + j * 384 + c * 64 + k8 * 8);
            *(uint4*)(Wt + ((j * 128 + k8 * 16) ^ ((j & 7) << 4))) = w;
        }
        __syncthreads();
#pragma unroll
        for (int ks = 0; ks < 2; ++ks) {
            bf16x8 a = *(bf16x8*)(rowsA + ((rA * 128 + ks * 64 + kb16) ^ rsw));
#pragma unroll
            for (int ct = 0; ct < 8; ++ct) {
                int j = ct * 16 + ln15;
                bf16x8 b = *(bf16x8*)(Wt + ((j * 128 + ks * 64 + kb16) ^ ((j & 7) << 4)));
                acc[ct] = __builtin_amdgcn_mfma_f32_16x16x32_bf16(a, b, acc[ct], 0, 0, 0);
            }
        }
    }
    __syncthreads();
    // epilogue: bias add, store, column stats
    const int jcol = ln15;
#pragma unroll
    for (int ct = 0; ct < 8; ++ct) {
        int j = ct * 16 + jcol;
        float bj = bias[j];
        float s = 0.0f, q = 0.0f;
#pragma unroll
        for (int r = 0; r < 4; ++r) {
            int n = n0 + wid * 16 + (lane >> 4) * 4 + r;
            if (n < N_NODES) {
                float v = acc[ct][r] + bj;
                h1p[n * DIM + j] = v;
                s += v; q += v * v;
            }
        }
        s += __shfl_xor(s, 16); s += __shfl_xor(s, 32);
        q += __shfl_xor(q, 16); q += __shfl_xor(q, 32);
        if ((lane >> 4) == 0) { atomicAdd(&s_sum[j], s); atomicAdd(&s_sq[j], q); }
    }
    __syncthreads();
    if (tid < 128) {
        atomicAdd(&stats[tid], s_sum[tid]);
        atomicAdd(&stats[128 + tid], s_sq[tid]);
    }
}

// ---------------- E: h1 = relu(BN1(h1p)); h2p = h1 @ W2 + b2; col stats2 ----------------
__global__ __launch_bounds__(256) void k_gemm2(const float* __restrict__ h1p,
                                               const ushort_t* __restrict__ W2t,
                                               const float* __restrict__ b2,
                                               const float* __restrict__ g1,
                                               const float* __restrict__ be1,
                                               float* __restrict__ h2p,
                                               float* __restrict__ stats) {
    __shared__ uint4 rowsA4[512];
    __shared__ uint4 Wt4[1024];
    __shared__ float bias[128];
    __shared__ float ssc[128], ssh[128];
    __shared__ float s_sum[128], s_sq[128];
    char* rowsA = (char*)rowsA4;
    char* Wt = (char*)Wt4;

    const int tid = threadIdx.x;
    const int wid = tid >> 6;
    const int lane = tid & 63;
    const int ln15 = lane & 15;
    const int kb16 = (lane >> 4) * 16;
    const int n0 = blockIdx.x * 64;
    const int rA = wid * 16 + ln15;
    const int rsw = (rA & 7) << 4;

    if (tid < 128) {
        float mu = stats[tid] * (1.0f / N_NODES);
        float var = stats[128 + tid] * (1.0f / N_NODES) - mu * mu;
        float sc = rsqrtf(var + EPS) * g1[tid];
        ssc[tid] = sc;
        ssh[tid] = be1[tid] - mu * sc;
        bias[tid] = b2[tid];
        s_sum[tid] = 0.0f; s_sq[tid] = 0.0f;
    }

    f32x4 acc[8];
#pragma unroll
    for (int i = 0; i < 8; ++i) acc[i] = (f32x4){0.0f, 0.0f, 0.0f, 0.0f};

    for (int c = 0; c < 2; ++c) {
        const int koff = c * 64;
        __syncthreads();
#pragma unroll
        for (int i = 0; i < 2; ++i) {
            int g = tid + i * 256;
            int r = g >> 3, k8 = g & 7;
            int n = n0 + r;
            float4 v0 = make_float4(0.f, 0.f, 0.f, 0.f), v1 = v0;
            if (n < N_NODES) {
                const float4* p = reinterpret_cast<const float4*>(h1p + n * DIM + koff + k8 * 8);
                float4 c0 = reinterpret_cast<const float4*>(ssc + koff + k8 * 8)[0];
                float4 c1 = reinterpret_cast<const float4*>(ssc + koff + k8 * 8)[1];
                float4 h0 = reinterpret_cast<const float4*>(ssh + koff + k8 * 8)[0];
                float4 h1 = reinterpret_cast<const float4*>(ssh + koff + k8 * 8)[1];
                v0 = p[0]; v1 = p[1];
                v0.x = fmaxf(v0.x * c0.x + h0.x, 0.f); v0.y = fmaxf(v0.y * c0.y + h0.y, 0.f);
                v0.z = fmaxf(v0.z * c0.z + h0.z, 0.f); v0.w = fmaxf(v0.w * c0.w + h0.w, 0.f);
                v1.x = fmaxf(v1.x * c1.x + h1.x, 0.f); v1.y = fmaxf(v1.y * c1.y + h1.y, 0.f);
                v1.z = fmaxf(v1.z * c1.z + h1.z, 0.f); v1.w = fmaxf(v1.w * c1.w + h1.w, 0.f);
            }
            ushort_t pk[8] = {f2bf(v0.x), f2bf(v0.y), f2bf(v0.z), f2bf(v0.w),
                              f2bf(v1.x), f2bf(v1.y), f2bf(v1.z), f2bf(v1.w)};
            *(uint4*)(rowsA + ((r * 128 + k8 * 16) ^ ((r & 7) << 4))) = *(const uint4*)pk;
        }
#pragma unroll
        for (int i = 0; i < 4; ++i) {
            int g = tid + i * 256;
            int j = g >> 3, k8 = g & 7;
            uint4 w = *reinterpret_cast<const uint4*>(W2t + j * 128 + c * 64 + k8 * 8);
            *(uint4*)(Wt + ((j * 128 + k8 * 16) ^ ((j & 7) << 4))) = w;
        }
        __syncthreads();
#pragma unroll
        for (int ks = 0; ks < 2; ++ks) {
            bf16x8 a = *(bf16x8*)(rowsA + ((rA * 128 + ks * 64 + kb16) ^ rsw));
#pragma unroll
            for (int ct = 0; ct < 8; ++ct) {
                int j = ct * 16 + ln15;
                bf16x8 b = *(bf16x8*)(Wt + ((j * 128 + ks * 64 + kb16) ^ ((j & 7) << 4)));
                acc[ct] = __builtin_amdgcn_mfma_f32_16x16x32_bf16(a, b, acc[ct], 0, 0, 0);
            }
        }
    }
    __syncthreads();
    const int jcol = ln15;
#pragma unroll
    for (int ct = 0; ct < 8; ++ct) {
        int j = ct * 16 + jcol;
        float bj = bias[j];
        float s = 0.0f, q = 0.0f;
#pragma unroll
        for (int r = 0; r < 4; ++r) {
            int n = n0 + wid * 16 + (lane >> 4) * 4 + r;
            if (n < N_NODES) {
                float v = acc[ct][r] + bj;
                h2p[n * DIM + j] = v;
                s += v; q += v * v;
            }
        }
        s += __shfl_xor(s, 16); s += __shfl_xor(s, 32);
        q += __shfl_xor(q, 16); q += __shfl_xor(q, 32);
        if ((lane >> 4) == 0) { atomicAdd(&s_sum[j], s); atomicAdd(&s_sq[j], q); }
    }
    __syncthreads();
    if (tid < 128) {
        atomicAdd(&stats[256 + tid], s_sum[tid]);
        atomicAdd(&stats[384 + tid], s_sq[tid]);
    }
}

// ---------------- F: h = relu(BN2(h2p)) -> out; att = sigmoid(h @ Wa + ba) ----------------
__global__ __launch_bounds__(256) void k_final(const float* __restrict__ h2p,
                                               const float* __restrict__ stats,
                                               const float* __restrict__ g2,
                                               const float* __restrict__ be2,
                                               const float* __restrict__ Wa,
                                               const float* __restrict__ ba,
                                               float* __restrict__ out) {
    const int lane = threadIdx.x & 63;
    const int wv = threadIdx.x >> 6;
    const int n = blockIdx.x * 4 + wv;
    if (n >= N_NODES) return;
    const int j0 = lane, j1 = lane + 64;

    float mu0 = stats[256 + j0] * (1.0f / N_NODES);
    float var0 = stats[384 + j0] * (1.0f / N_NODES) - mu0 * mu0;
    float sc0 = rsqrtf(var0 + EPS) * g2[j0];
    float sh0 = be2[j0] - mu0 * sc0;
    float mu1 = stats[256 + j1] * (1.0f / N_NODES);
    float var1 = stats[384 + j1] * (1.0f / N_NODES) - mu1 * mu1;
    float sc1 = rsqrtf(var1 + EPS) * g2[j1];
    float sh1 = be2[j1] - mu1 * sc1;

    float v0 = fmaxf(h2p[n * DIM + j0] * sc0 + sh0, 0.0f);
    float v1 = fmaxf(h2p[n * DIM + j1] * sc1 + sh1, 0.0f);
    out[n * DIM + j0] = v0;
    out[n * DIM + j1] = v1;

    float p = v0 * Wa[j0] + v1 * Wa[j1];
#pragma unroll
    for (int off = 32; off > 0; off >>= 1) p += __shfl_down(p, off);
    if (lane == 0) out[N_NODES * DIM + n] = 1.0f / (1.0f + expf(-(p + ba[0])));
}

extern "C" void kernel_launch(void* const* d_in, const int* in_sizes, int n_in,
                              void* d_out, int out_size, void* d_ws, size_t ws_size,
                              hipStream_t stream) {
    const float* x   = (const float*)d_in[0];
    const float* msg = (const float*)d_in[1];
    const float* W1  = (const float*)d_in[2];
    const float* b1  = (const float*)d_in[3];
    const float* g1  = (const float*)d_in[4];
    const float* be1 = (const float*)d_in[5];
    const float* W2  = (const float*)d_in[6];
    const float* b2  = (const float*)d_in[7];
    const float* g2  = (const float*)d_in[8];
    const float* be2 = (const float*)d_in[9];
    const float* Wa  = (const float*)d_in[10];
    const float* ba  = (const float*)d_in[11];
    const int*   ei  = (const int*)d_in[12];

    float*    ws    = (float*)d_ws;
    float*    stats = ws;                            // 512 floats
    float*    fwd   = ws + 512;                      // N*H
    float*    bwd   = fwd + N_NODES * DIM;           // N*H
    int*      cnt   = (int*)(bwd + N_NODES * DIM);   // 2N
    int*      slots = cnt + 2 * N_NODES;             // 2N * CAP (51.2 MB)
    ushort_t* W1t   = (ushort_t*)(slots + 2 * N_NODES * CAP);  // 128*384 bf16
    ushort_t* W2t   = W1t + 128 * 384;               // 128*128 bf16

    float* h1p = (float*)d_out;                      // scratch in out buffer
    float* h2p = fwd;                                // fwd dead after gemm1
    float* out = (float*)d_out;

    k_init<<<(2 * N_NODES + 255) / 256, 256, 0, stream>>>(stats, cnt);
    k_prep<<<(128 * 384 + 128 * 128 + 255) / 256, 256, 0, stream>>>(W1, W2, W1t, W2t);
    k_bucket<<<(N_EDGES / 4 + 255) / 256, 256, 0, stream>>>(ei, cnt, slots);
    k_gather<<<(2 * N_NODES) / 4, 256, 0, stream>>>((const float4*)msg, slots, cnt, fwd, bwd);
    k_gemm1<<<(N_NODES + 63) / 64, 256, 0, stream>>>(x, fwd, bwd, W1t, b1, h1p, stats);
    k_gemm2<<<(N_NODES + 63) / 64, 256, 0, stream>>>(h1p, W2t, b2, g1, be1, h2p, stats);
    k_final<<<(N_NODES + 3) / 4, 256, 0, stream>>>(h2p, stats, g2, be2, Wa, ba, out);
}

// Round 8
// 621.170 us; speedup vs baseline: 13.5815x; 1.1020x over previous
//
#include <hip/hip_runtime.h>
#include <math.h>

#define N_NODES 50000
#define N_EDGES 1600000
#define DIM 128          // D == H == 128
#define EPS 1e-5f
#define CAP 96           // bucket capacity; P(Poisson(32) >= 96) ~ 1e-18/bucket

typedef short bf16x8 __attribute__((ext_vector_type(8)));
typedef float f32x4 __attribute__((ext_vector_type(4)));
typedef int i32x4 __attribute__((ext_vector_type(4)));
typedef unsigned short ushort_t;

__device__ __forceinline__ f32x4 v4max(f32x4 a, f32x4 b) {
    f32x4 r;
    r[0] = fmaxf(a[0], b[0]); r[1] = fmaxf(a[1], b[1]);
    r[2] = fmaxf(a[2], b[2]); r[3] = fmaxf(a[3], b[3]);
    return r;
}

// fp32 -> bf16 round-to-nearest-even
__device__ __forceinline__ ushort_t f2bf(float f) {
    unsigned int u = __float_as_uint(f);
    return (ushort_t)((u + 0x7FFFu + ((u >> 16) & 1u)) >> 16);
}
__device__ __forceinline__ float bf2f(ushort_t u) {
    return __uint_as_float(((unsigned int)u) << 16);
}

// ---------------- A: W1 -> W1t bf16 [128j][384k]; W2 -> W2t bf16 [128j][128k] ----------------
__global__ __launch_bounds__(256) void k_prep(const float* __restrict__ W1, const float* __restrict__ W2,
                                              ushort_t* __restrict__ W1t, ushort_t* __restrict__ W2t) {
    int gid = blockIdx.x * 256 + threadIdx.x;
    if (gid < 128 * 384) {
        int j = gid / 384, k = gid % 384;
        W1t[gid] = f2bf(W1[k * 128 + j]);
    } else {
        int g2 = gid - 128 * 384;
        if (g2 < 128 * 128) {
            int j = g2 / 128, k = g2 % 128;
            W2t[g2] = f2bf(W2[k * 128 + j]);
        }
    }
}

// ---------------- B: bucket edges by col (fwd) and row (bwd), fixed stride CAP ----------------
__global__ __launch_bounds__(256) void k_bucket(const int* __restrict__ ei, int* __restrict__ cnt,
                                                int* __restrict__ slots) {
    int t = blockIdx.x * 256 + threadIdx.x;
    if (t >= N_EDGES / 4) return;
    int4 r4 = reinterpret_cast<const int4*>(ei)[t];
    int4 c4 = reinterpret_cast<const int4*>(ei + N_EDGES)[t];
    int e = t * 4;
    slots[c4.x * CAP + atomicAdd(&cnt[c4.x], 1)] = e + 0;
    slots[c4.y * CAP + atomicAdd(&cnt[c4.y], 1)] = e + 1;
    slots[c4.z * CAP + atomicAdd(&cnt[c4.z], 1)] = e + 2;
    slots[c4.w * CAP + atomicAdd(&cnt[c4.w], 1)] = e + 3;
    slots[(N_NODES + r4.x) * CAP + atomicAdd(&cnt[N_NODES + r4.x], 1)] = e + 0;
    slots[(N_NODES + r4.y) * CAP + atomicAdd(&cnt[N_NODES + r4.y], 1)] = e + 1;
    slots[(N_NODES + r4.z) * CAP + atomicAdd(&cnt[N_NODES + r4.z], 1)] = e + 2;
    slots[(N_NODES + r4.w) * CAP + atomicAdd(&cnt[N_NODES + r4.w], 1)] = e + 3;
}

// ---------------- C: gather-max. wave = (node,dir); nt loads; 8 rows in flight/half ----------------
__global__ __launch_bounds__(256) void k_gather(const f32x4* __restrict__ msgv,
                                                const int* __restrict__ slots,
                                                const int* __restrict__ cnt,
                                                ushort_t* __restrict__ fwd,
                                                ushort_t* __restrict__ bwd) {
    const int wid = blockIdx.x * 4 + (threadIdx.x >> 6);   // 0 .. 2N-1
    const int dir = (wid >= N_NODES);
    const int n = dir ? wid - N_NODES : wid;
    const int lane = threadIdx.x & 63;
    const int q = lane & 31;        // channel quad
    const int h = lane >> 5;        // half-wave id
    const int c = cnt[dir * N_NODES + n];
    const int* el = slots + (size_t)(dir * N_NODES + n) * CAP;

    f32x4 acc0 = {-INFINITY, -INFINITY, -INFINITY, -INFINITY};
    f32x4 acc1 = acc0;
    const int nfull = c >> 2;
    int g = h;
    // 2 groups (8 rows) in flight per half-wave
    for (; g + 2 < nfull; g += 4) {
        i32x4 ea = *reinterpret_cast<const i32x4*>(el + g * 4);
        i32x4 eb = *reinterpret_cast<const i32x4*>(el + (g + 2) * 4);
        f32x4 m0 = __builtin_nontemporal_load(&msgv[(size_t)ea[0] * 32 + q]);
        f32x4 m1 = __builtin_nontemporal_load(&msgv[(size_t)ea[1] * 32 + q]);
        f32x4 m2 = __builtin_nontemporal_load(&msgv[(size_t)ea[2] * 32 + q]);
        f32x4 m3 = __builtin_nontemporal_load(&msgv[(size_t)ea[3] * 32 + q]);
        f32x4 m4 = __builtin_nontemporal_load(&msgv[(size_t)eb[0] * 32 + q]);
        f32x4 m5 = __builtin_nontemporal_load(&msgv[(size_t)eb[1] * 32 + q]);
        f32x4 m6 = __builtin_nontemporal_load(&msgv[(size_t)eb[2] * 32 + q]);
        f32x4 m7 = __builtin_nontemporal_load(&msgv[(size_t)eb[3] * 32 + q]);
        acc0 = v4max(acc0, v4max(v4max(m0, m1), v4max(m2, m3)));
        acc1 = v4max(acc1, v4max(v4max(m4, m5), v4max(m6, m7)));
    }
    for (; g < nfull; g += 2) {
        i32x4 e4 = *reinterpret_cast<const i32x4*>(el + g * 4);
        f32x4 m0 = __builtin_nontemporal_load(&msgv[(size_t)e4[0] * 32 + q]);
        f32x4 m1 = __builtin_nontemporal_load(&msgv[(size_t)e4[1] * 32 + q]);
        f32x4 m2 = __builtin_nontemporal_load(&msgv[(size_t)e4[2] * 32 + q]);
        f32x4 m3 = __builtin_nontemporal_load(&msgv[(size_t)e4[3] * 32 + q]);
        acc0 = v4max(acc0, v4max(v4max(m0, m1), v4max(m2, m3)));
    }
    if (h == (nfull & 1)) {
        for (int p = nfull * 4; p < c; ++p) {
            acc1 = v4max(acc1, __builtin_nontemporal_load(&msgv[(size_t)el[p] * 32 + q]));
        }
    }
    f32x4 acc = v4max(acc0, acc1);
    acc[0] = fmaxf(acc[0], __shfl_xor(acc[0], 32));
    acc[1] = fmaxf(acc[1], __shfl_xor(acc[1], 32));
    acc[2] = fmaxf(acc[2], __shfl_xor(acc[2], 32));
    acc[3] = fmaxf(acc[3], __shfl_xor(acc[3], 32));

    if (h == 0) {
        if (c == 0) { acc[0] = 0.f; acc[1] = 0.f; acc[2] = 0.f; acc[3] = 0.f; }
        ushort_t pk[4] = {f2bf(acc[0]), f2bf(acc[1]), f2bf(acc[2]), f2bf(acc[3])};
        ushort_t* dst = (dir ? bwd : fwd) + n * DIM + q * 4;
        *reinterpret_cast<uint2*>(dst) = *reinterpret_cast<const uint2*>(pk);
    }
}

// ======== MFMA GEMM core (64 rows x 128 cols per block, 4 waves, 16x16x32 bf16) ========
// LDS tiles XOR-swizzled: byte ^= ((row&7)<<4).

// ---------------- D: h1b = bf16([x|fwd|bwd] @ W1 + b1), col stats ----------------
__global__ __launch_bounds__(256) void k_gemm1(const float* __restrict__ x,
                                               const ushort_t* __restrict__ fwd,
                                               const ushort_t* __restrict__ bwd,
                                               const ushort_t* __restrict__ W1t,
                                               const float* __restrict__ b1,
                                               ushort_t* __restrict__ h1b,
                                               float* __restrict__ stats) {
    __shared__ uint4 rowsA4[512];      // 64 rows x 64 k bf16 (8 KB), swizzled
    __shared__ uint4 Wt4[1024];        // 128 j x 64 k bf16 (16 KB), swizzled
    __shared__ float bias[128];
    __shared__ float s_sum[128], s_sq[128];
    char* rowsA = (char*)rowsA4;
    char* Wt = (char*)Wt4;

    const int tid = threadIdx.x;
    const int wid = tid >> 6;
    const int lane = tid & 63;
    const int ln15 = lane & 15;
    const int kb16 = (lane >> 4) * 16;
    const int n0 = blockIdx.x * 64;
    const int rA = wid * 16 + ln15;
    const int rsw = (rA & 7) << 4;

    if (tid < 128) { bias[tid] = b1[tid]; s_sum[tid] = 0.0f; s_sq[tid] = 0.0f; }

    f32x4 acc[8];
#pragma unroll
    for (int i = 0; i < 8; ++i) acc[i] = (f32x4){0.0f, 0.0f, 0.0f, 0.0f};

    for (int c = 0; c < 6; ++c) {
        const int koff = (c & 1) * 64;
        __syncthreads();
        if (c < 2) {
            // stage x rows (fp32 -> bf16)
#pragma unroll
            for (int i = 0; i < 2; ++i) {
                int g = tid + i * 256;
                int r = g >> 3, k8 = g & 7;
                int n = n0 + r;
                f32x4 v0 = {0.f, 0.f, 0.f, 0.f}, v1 = v0;
                if (n < N_NODES) {
                    const f32x4* p = reinterpret_cast<const f32x4*>(x + n * DIM + koff + k8 * 8);
                    v0 = __builtin_nontemporal_load(p);
                    v1 = __builtin_nontemporal_load(p + 1);
                }
                ushort_t pk[8] = {f2bf(v0[0]), f2bf(v0[1]), f2bf(v0[2]), f2bf(v0[3]),
                                  f2bf(v1[0]), f2bf(v1[1]), f2bf(v1[2]), f2bf(v1[3])};
                *(uint4*)(rowsA + ((r * 128 + k8 * 16) ^ ((r & 7) << 4))) = *(const uint4*)pk;
            }
        } else {
            // stage fwd/bwd rows (already bf16)
            const ushort_t* src16 = (c < 4) ? fwd : bwd;
#pragma unroll
            for (int i = 0; i < 2; ++i) {
                int g = tid + i * 256;
                int r = g >> 3, k8 = g & 7;
                int n = n0 + r;
                uint4 v = make_uint4(0u, 0u, 0u, 0u);
                if (n < N_NODES) v = *reinterpret_cast<const uint4*>(src16 + n * DIM + koff + k8 * 8);
                *(uint4*)(rowsA + ((r * 128 + k8 * 16) ^ ((r & 7) << 4))) = v;
            }
        }
        // stage W1t chunk
#pragma unroll
        for (int i = 0; i < 4; ++i) {
            int g = tid + i * 256;
            int j = g >> 3, k8 = g & 7;
            uint4 w = *reinterpret_cast<const uint4*>(W1t + j * 384 + c * 64 + k8 * 8);
            *(uint4*)(Wt + ((j * 128 + k8 * 16) ^ ((j & 7) << 4))) = w;
        }
        __syncthreads();
#pragma unroll
        for (int ks = 0; ks < 2; ++ks) {
            bf16x8 a = *(bf16x8*)(rowsA + ((rA * 128 + ks * 64 + kb16) ^ rsw));
#pragma unroll
            for (int ct = 0; ct < 8; ++ct) {
                int j = ct * 16 + ln15;
                bf16x8 b = *(bf16x8*)(Wt + ((j * 128 + ks * 64 + kb16) ^ ((j & 7) << 4)));
                acc[ct] = __builtin_amdgcn_mfma_f32_16x16x32_bf16(a, b, acc[ct], 0, 0, 0);
            }
        }
    }
    __syncthreads();
    const int jcol = ln15;
#pragma unroll
    for (int ct = 0; ct < 8; ++ct) {
        int j = ct * 16 + jcol;
        float bj = bias[j];
        float s = 0.0f, q = 0.0f;
#pragma unroll
        for (int r = 0; r < 4; ++r) {
            int n = n0 + wid * 16 + (lane >> 4) * 4 + r;
            if (n < N_NODES) {
                float v = acc[ct][r] + bj;
                h1b[n * DIM + j] = f2bf(v);
                s += v; q += v * v;
            }
        }
        s += __shfl_xor(s, 16); s += __shfl_xor(s, 32);
        q += __shfl_xor(q, 16); q += __shfl_xor(q, 32);
        if ((lane >> 4) == 0) { atomicAdd(&s_sum[j], s); atomicAdd(&s_sq[j], q); }
    }
    __syncthreads();
    if (tid < 128) {
        atomicAdd(&stats[tid], s_sum[tid]);
        atomicAdd(&stats[128 + tid], s_sq[tid]);
    }
}

// ---------------- E: h1 = relu(BN1(h1b)); h2b = bf16(h1 @ W2 + b2); col stats2 ----------------
__global__ __launch_bounds__(256) void k_gemm2(const ushort_t* __restrict__ h1b,
                                               const ushort_t* __restrict__ W2t,
                                               const float* __restrict__ b2,
                                               const float* __restrict__ g1,
                                               const float* __restrict__ be1,
                                               ushort_t* __restrict__ h2b,
                                               float* __restrict__ stats) {
    __shared__ uint4 rowsA4[512];
    __shared__ uint4 Wt4[1024];
    __shared__ float bias[128];
    __shared__ float ssc[128], ssh[128];
    __shared__ float s_sum[128], s_sq[128];
    char* rowsA = (char*)rowsA4;
    char* Wt = (char*)Wt4;

    const int tid = threadIdx.x;
    const int wid = tid >> 6;
    const int lane = tid & 63;
    const int ln15 = lane & 15;
    const int kb16 = (lane >> 4) * 16;
    const int n0 = blockIdx.x * 64;
    const int rA = wid * 16 + ln15;
    const int rsw = (rA & 7) << 4;

    if (tid < 128) {
        float mu = stats[tid] * (1.0f / N_NODES);
        float var = stats[128 + tid] * (1.0f / N_NODES) - mu * mu;
        float sc = rsqrtf(var + EPS) * g1[tid];
        ssc[tid] = sc;
        ssh[tid] = be1[tid] - mu * sc;
        bias[tid] = b2[tid];
        s_sum[tid] = 0.0f; s_sq[tid] = 0.0f;
    }

    f32x4 acc[8];
#pragma unroll
    for (int i = 0; i < 8; ++i) acc[i] = (f32x4){0.0f, 0.0f, 0.0f, 0.0f};

    for (int c = 0; c < 2; ++c) {
        const int koff = c * 64;
        __syncthreads();
#pragma unroll
        for (int i = 0; i < 2; ++i) {
            int g = tid + i * 256;
            int r = g >> 3, k8 = g & 7;
            int n = n0 + r;
            ushort_t pk[8] = {0, 0, 0, 0, 0, 0, 0, 0};
            if (n < N_NODES) {
                uint4 raw = *reinterpret_cast<const uint4*>(h1b + n * DIM + koff + k8 * 8);
                const ushort_t* rp = (const ushort_t*)&raw;
#pragma unroll
                for (int t = 0; t < 8; ++t) {
                    int kk = koff + k8 * 8 + t;
                    float v = fmaxf(bf2f(rp[t]) * ssc[kk] + ssh[kk], 0.0f);
                    pk[t] = f2bf(v);
                }
            }
            *(uint4*)(rowsA + ((r * 128 + k8 * 16) ^ ((r & 7) << 4))) = *(const uint4*)pk;
        }
#pragma unroll
        for (int i = 0; i < 4; ++i) {
            int g = tid + i * 256;
            int j = g >> 3, k8 = g & 7;
            uint4 w = *reinterpret_cast<const uint4*>(W2t + j * 128 + c * 64 + k8 * 8);
            *(uint4*)(Wt + ((j * 128 + k8 * 16) ^ ((j & 7) << 4))) = w;
        }
        __syncthreads();
#pragma unroll
        for (int ks = 0; ks < 2; ++ks) {
            bf16x8 a = *(bf16x8*)(rowsA + ((rA * 128 + ks * 64 + kb16) ^ rsw));
#pragma unroll
            for (int ct = 0; ct < 8; ++ct) {
                int j = ct * 16 + ln15;
                bf16x8 b = *(bf16x8*)(Wt + ((j * 128 + ks * 64 + kb16) ^ ((j & 7) << 4)));
                acc[ct] = __builtin_amdgcn_mfma_f32_16x16x32_bf16(a, b, acc[ct], 0, 0, 0);
            }
        }
    }
    __syncthreads();
    const int jcol = ln15;
#pragma unroll
    for (int ct = 0; ct < 8; ++ct) {
        int j = ct * 16 + jcol;
        float bj = bias[j];
        float s = 0.0f, q = 0.0f;
#pragma unroll
        for (int r = 0; r < 4; ++r) {
            int n = n0 + wid * 16 + (lane >> 4) * 4 + r;
            if (n < N_NODES) {
                float v = acc[ct][r] + bj;
                h2b[n * DIM + j] = f2bf(v);
                s += v; q += v * v;
            }
        }
        s += __shfl_xor(s, 16); s += __shfl_xor(s, 32);
        q += __shfl_xor(q, 16); q += __shfl_xor(q, 32);
        if ((lane >> 4) == 0) { atomicAdd(&s_sum[j], s); atomicAdd(&s_sq[j], q); }
    }
    __syncthreads();
    if (tid < 128) {
        atomicAdd(&stats[256 + tid], s_sum[tid]);
        atomicAdd(&stats[384 + tid], s_sq[tid]);
    }
}

// ---------------- F: h = relu(BN2(h2b)) -> out; att = sigmoid(h @ Wa + ba) ----------------
__global__ __launch_bounds__(256) void k_final(const ushort_t* __restrict__ h2b,
                                               const float* __restrict__ stats,
                                               const float* __restrict__ g2,
                                               const float* __restrict__ be2,
                                               const float* __restrict__ Wa,
                                               const float* __restrict__ ba,
                                               float* __restrict__ out) {
    const int lane = threadIdx.x & 63;
    const int wv = threadIdx.x >> 6;
    const int n = blockIdx.x * 4 + wv;
    if (n >= N_NODES) return;
    const int j0 = lane, j1 = lane + 64;

    float mu0 = stats[256 + j0] * (1.0f / N_NODES);
    float var0 = stats[384 + j0] * (1.0f / N_NODES) - mu0 * mu0;
    float sc0 = rsqrtf(var0 + EPS) * g2[j0];
    float sh0 = be2[j0] - mu0 * sc0;
    float mu1 = stats[256 + j1] * (1.0f / N_NODES);
    float var1 = stats[384 + j1] * (1.0f / N_NODES) - mu1 * mu1;
    float sc1 = rsqrtf(var1 + EPS) * g2[j1];
    float sh1 = be2[j1] - mu1 * sc1;

    float v0 = fmaxf(bf2f(h2b[n * DIM + j0]) * sc0 + sh0, 0.0f);
    float v1 = fmaxf(bf2f(h2b[n * DIM + j1]) * sc1 + sh1, 0.0f);
    out[n * DIM + j0] = v0;
    out[n * DIM + j1] = v1;

    float p = v0 * Wa[j0] + v1 * Wa[j1];
#pragma unroll
    for (int off = 32; off > 0; off >>= 1) p += __shfl_down(p, off);
    if (lane == 0) out[N_NODES * DIM + n] = 1.0f / (1.0f + expf(-(p + ba[0])));
}

extern "C" void kernel_launch(void* const* d_in, const int* in_sizes, int n_in,
                              void* d_out, int out_size, void* d_ws, size_t ws_size,
                              hipStream_t stream) {
    const float* x   = (const float*)d_in[0];
    const float* msg = (const float*)d_in[1];
    const float* W1  = (const float*)d_in[2];
    const float* b1  = (const float*)d_in[3];
    const float* g1  = (const float*)d_in[4];
    const float* be1 = (const float*)d_in[5];
    const float* W2  = (const float*)d_in[6];
    const float* b2  = (const float*)d_in[7];
    const float* g2  = (const float*)d_in[8];
    const float* be2 = (const float*)d_in[9];
    const float* Wa  = (const float*)d_in[10];
    const float* ba  = (const float*)d_in[11];
    const int*   ei  = (const int*)d_in[12];

    float*    stats = (float*)d_ws;                          // 512 f
    ushort_t* fwdb  = (ushort_t*)(stats + 512);              // N*128 bf16
    ushort_t* bwdb  = fwdb + N_NODES * DIM;                  // N*128 bf16
    int*      cnt   = (int*)(bwdb + N_NODES * DIM);          // 2N
    int*      slots = cnt + 2 * N_NODES;                     // 2N*CAP (38.4 MB)
    ushort_t* W1t   = (ushort_t*)(slots + 2 * N_NODES * CAP);
    ushort_t* W2t   = W1t + 128 * 384;

    ushort_t* h1b = (ushort_t*)d_out;                        // 12.8 MB scratch in out buffer
    ushort_t* h2b = fwdb;                                    // fwd dead after gemm1
    float*    out = (float*)d_out;

    (void)hipMemsetAsync(stats, 0, 512 * sizeof(float), stream);
    (void)hipMemsetAsync(cnt, 0, 2 * N_NODES * sizeof(int), stream);
    k_prep<<<(128 * 384 + 128 * 128 + 255) / 256, 256, 0, stream>>>(W1, W2, W1t, W2t);
    k_bucket<<<(N_EDGES / 4 + 255) / 256, 256, 0, stream>>>(ei, cnt, slots);
    k_gather<<<(2 * N_NODES) / 4, 256, 0, stream>>>((const f32x4*)msg, slots, cnt, fwdb, bwdb);
    k_gemm1<<<(N_NODES + 63) / 64, 256, 0, stream>>>(x, fwdb, bwdb, W1t, b1, h1b, stats);
    k_gemm2<<<(N_NODES + 63) / 64, 256, 0, stream>>>(h1b, W2t, b2, g1, be1, h2b, stats);
    k_final<<<(N_NODES + 3) / 4, 256, 0, stream>>>(h2b, stats, g2, be2, Wa, ba, out);
}